// Round 2
// baseline (1514.147 us; speedup 1.0000x reference)
//
#include <hip/hip_runtime.h>
#include <hip/hip_bf16.h>
#include <cstdint>

#define MB 8
#define TT 2048
#define DIMK 1024
#define CC 128
#define GG 16
#define MROWS (MB*TT)   /* 16384 */
#define NPROJ 576
#define YSTR 576

// ---------------------------------------------------------------------------
// Pack weights: Wcat[k][n] n in [0,576): 0-127 Wq, 128-255 Wk, 256-383 Wv,
// 384-511 Wg, 512 Wa, 513 Wb, rest 0.
// ---------------------------------------------------------------------------
__global__ void pack_w(const float* __restrict__ Wq, const float* __restrict__ Wk,
                       const float* __restrict__ Wv, const float* __restrict__ Wg,
                       const float* __restrict__ Wa, const float* __restrict__ Wb,
                       float* __restrict__ Wcat)
{
    int idx = blockIdx.x * 256 + threadIdx.x;
    if (idx >= DIMK * NPROJ) return;
    int k = idx / NPROJ, n = idx % NPROJ;
    float v = 0.f;
    if      (n < 128) v = Wq[k * 128 + n];
    else if (n < 256) v = Wk[k * 128 + (n - 128)];
    else if (n < 384) v = Wv[k * 128 + (n - 256)];
    else if (n < 512) v = Wg[k * 128 + (n - 384)];
    else if (n == 512) v = Wa[k];
    else if (n == 513) v = Wb[k];
    Wcat[idx] = v;
}

__global__ void pack_bias(const float* __restrict__ bq, const float* __restrict__ bk,
                          const float* __restrict__ bv, const float* __restrict__ bg,
                          const float* __restrict__ ba, const float* __restrict__ bb,
                          float* __restrict__ biascat)
{
    int n = threadIdx.x;
    if (n >= NPROJ) return;
    float v = 0.f;
    if      (n < 128) v = bq[n];
    else if (n < 256) v = bk[n - 128];
    else if (n < 384) v = bv[n - 256];
    else if (n < 512) v = bg[n - 384];
    else if (n == 512) v = ba[0];
    else if (n == 513) v = bb[0];
    biascat[n] = v;
}

// ---------------------------------------------------------------------------
// Tiled fp32 SGEMM: C[M][N] = A[M][K] @ B[K][N] + bias[N]
// Tile 128(M) x 64(N), BK=16, 256 threads, 8x4 per thread.
// ---------------------------------------------------------------------------
__global__ __launch_bounds__(256) void sgemm_bias(
    const float* __restrict__ A, const float* __restrict__ Bm,
    const float* __restrict__ bias, float* __restrict__ Cm,
    int M, int N, int K)
{
    __shared__ float As[16][128];
    __shared__ float Bs[16][64];
    int tid = threadIdx.x;
    int bm = blockIdx.y * 128;
    int bn = blockIdx.x * 64;
    int tx = tid & 15, ty = tid >> 4;
    float acc[8][4];
#pragma unroll
    for (int u = 0; u < 8; u++)
#pragma unroll
        for (int w = 0; w < 4; w++) acc[u][w] = 0.f;

    for (int kk = 0; kk < K; kk += 16) {
#pragma unroll
        for (int j = 0; j < 2; j++) {
            int fid = tid * 2 + j;
            int row = fid >> 2, kq = fid & 3;
            const float4 av = *(const float4*)(A + (size_t)(bm + row) * K + kk + kq * 4);
            As[kq * 4 + 0][row] = av.x;
            As[kq * 4 + 1][row] = av.y;
            As[kq * 4 + 2][row] = av.z;
            As[kq * 4 + 3][row] = av.w;
        }
        {
            int krow = tid >> 4, c4 = tid & 15;
            const float4 bv = *(const float4*)(Bm + (size_t)(kk + krow) * N + bn + c4 * 4);
            *(float4*)&Bs[krow][c4 * 4] = bv;
        }
        __syncthreads();
#pragma unroll
        for (int kc = 0; kc < 16; kc++) {
            float4 a0 = *(const float4*)&As[kc][ty * 8];
            float4 a1 = *(const float4*)&As[kc][ty * 8 + 4];
            float4 bv = *(const float4*)&Bs[kc][tx * 4];
            float av[8] = {a0.x, a0.y, a0.z, a0.w, a1.x, a1.y, a1.z, a1.w};
            float bw[4] = {bv.x, bv.y, bv.z, bv.w};
#pragma unroll
            for (int u = 0; u < 8; u++)
#pragma unroll
                for (int w = 0; w < 4; w++)
                    acc[u][w] += av[u] * bw[w];
        }
        __syncthreads();
    }
    float4 b4 = *(const float4*)(bias + bn + tx * 4);
#pragma unroll
    for (int u = 0; u < 8; u++) {
        float4 r = make_float4(acc[u][0] + b4.x, acc[u][1] + b4.y,
                               acc[u][2] + b4.z, acc[u][3] + b4.w);
        *(float4*)(Cm + (size_t)(bm + ty * 8 + u) * N + bn + tx * 4) = r;
    }
}

// ---------------------------------------------------------------------------
// Post-projection: k row-normalize, sigmoid(g), pack q/v per (group,t) into
// broadcast float4 records, pack (alpha,beta) into float2.
// One wave per row m = b*TT+t.
// ---------------------------------------------------------------------------
__global__ __launch_bounds__(64) void postproj_kernel(
    const float* __restrict__ Y, float* __restrict__ knorm,
    float* __restrict__ gbuf, float4* __restrict__ qvpack,
    float2* __restrict__ abpack)
{
    int m = blockIdx.x;
    int lane = threadIdx.x;
    int b = m >> 11, t = m & (TT - 1);
    const float* yr = Y + (size_t)m * YSTR;
    float k0 = yr[128 + lane], k1 = yr[192 + lane];
    float ss = k0 * k0 + k1 * k1;
#pragma unroll
    for (int mask = 1; mask < 64; mask <<= 1) ss += __shfl_xor(ss, mask);
    float inv = 1.0f / fmaxf(sqrtf(ss), 1e-12f);
    knorm[(size_t)m * CC + lane]      = k0 * inv;
    knorm[(size_t)m * CC + 64 + lane] = k1 * inv;
    float g0 = yr[384 + lane], g1 = yr[448 + lane];
    gbuf[(size_t)m * CC + lane]      = 1.f / (1.f + expf(-g0));
    gbuf[(size_t)m * CC + 64 + lane] = 1.f / (1.f + expf(-g1));
    // qv pack: lane = g*4+ig -> (q[i0], q[i0+1], v[i0], v[i0+1]), i0=g*8+ig*2
    {
        int g = lane >> 2, ig = lane & 3;
        int i0 = g * 8 + ig * 2;
        float4 r = make_float4(yr[i0], yr[i0 + 1], yr[256 + i0], yr[256 + i0 + 1]);
        qvpack[((size_t)(b * GG + g) * TT + t) * 4 + ig] = r;
    }
    if (lane == 0) {
        float a = 1.f / (1.f + expf(-yr[512]));
        float bb_ = 1.f / (1.f + expf(-yr[513]));
        abpack[(size_t)b * TT + t] = make_float2(a, bb_);
    }
}

// ---------------------------------------------------------------------------
// Sequential scan, software-pipelined with prefetch depth D.
// Grid = MB*GG single-wave blocks. Block (b,gi) owns rows [gi*8, gi*8+8).
// Lane layout: jg=lane&15 (8 cols each), ig=lane>>4 (2 rows each).
// ---------------------------------------------------------------------------
#define PFD 8

template <bool ATOMIC>
__global__ __launch_bounds__(64) void scan_kernel(
    const float* __restrict__ knorm, const float4* __restrict__ qvpack,
    const float2* __restrict__ abpack, void* __restrict__ outp)
{
    int blk = blockIdx.x;
    int b = blk >> 4;
    int gi = blk & 15;
    int lane = threadIdx.x;
    int jg = lane & 15, ig = lane >> 4;
    float s0[8], s1[8];
#pragma unroll
    for (int c = 0; c < 8; c++) { s0[c] = 0.f; s1[c] = 0.f; }
    size_t mbase = (size_t)b * TT;

    const float* knb = knorm + mbase * CC + jg * 8;
    const float4* qvb = qvpack + (size_t)blk * TT * 4 + ig;
    const float2* abb = abpack + mbase;

    float4 kaB[PFD], kbB[PFD], qvB[PFD];
    float2 abB[PFD];
#pragma unroll
    for (int u = 0; u < PFD; u++) {
        kaB[u] = *(const float4*)(knb + (size_t)u * CC);
        kbB[u] = *(const float4*)(knb + (size_t)u * CC + 4);
        qvB[u] = qvb[(size_t)u * 4];
        abB[u] = abb[u];
    }

    for (int t = 0; t < TT; t += PFD) {
#pragma unroll
        for (int u = 0; u < PFD; u++) {
            float4 ka = kaB[u], kb = kbB[u], qv = qvB[u];
            float2 ab = abB[u];
            int tp = t + u + PFD;
            if (tp < TT) {
                kaB[u] = *(const float4*)(knb + (size_t)tp * CC);
                kbB[u] = *(const float4*)(knb + (size_t)tp * CC + 4);
                qvB[u] = qvb[(size_t)tp * 4];
                abB[u] = abb[tp];
            }
            float at = ab.x, bt = ab.y;
            float q0 = qv.x, q1 = qv.y, v0 = qv.z, v1 = qv.w;
            float k[8] = {ka.x, ka.y, ka.z, ka.w, kb.x, kb.y, kb.z, kb.w};
            // Sk_i = S[i,:] . k  — tree over 8 in-lane + 4 shuffle levels
            float pr0[8], pr1[8];
#pragma unroll
            for (int c = 0; c < 8; c++) { pr0[c] = s0[c] * k[c]; pr1[c] = s1[c] * k[c]; }
            float p0 = ((pr0[0] + pr0[1]) + (pr0[2] + pr0[3])) +
                       ((pr0[4] + pr0[5]) + (pr0[6] + pr0[7]));
            float p1 = ((pr1[0] + pr1[1]) + (pr1[2] + pr1[3])) +
                       ((pr1[4] + pr1[5]) + (pr1[6] + pr1[7]));
#pragma unroll
            for (int mask = 1; mask < 16; mask <<= 1) {
                p0 += __shfl_xor(p0, mask);
                p1 += __shfl_xor(p1, mask);
            }
            float c0 = bt * (v0 - at * p0);
            float c1 = bt * (v1 - at * p1);
            float po[8];
#pragma unroll
            for (int c = 0; c < 8; c++) {
                s0[c] = at * s0[c] + c0 * k[c];
                s1[c] = at * s1[c] + c1 * k[c];
                po[c] = q0 * s0[c] + q1 * s1[c];
            }
#pragma unroll
            for (int c = 0; c < 8; c++) {
                po[c] += __shfl_xor(po[c], 16);
                po[c] += __shfl_xor(po[c], 32);
            }
            size_t m = mbase + t + u;
            if (ATOMIC) {
                if (ig == 0) {
                    float* op = (float*)outp + m * CC + jg * 8;
#pragma unroll
                    for (int c = 0; c < 8; c++) atomicAdd(op + c, po[c]);
                }
            } else {
                if (ig == 0) {
                    unsigned pk[4];
#pragma unroll
                    for (int c = 0; c < 4; c++) {
                        unsigned ux = __float_as_uint(po[2 * c]);
                        ux += 0x7fffu + ((ux >> 16) & 1u);
                        unsigned uy = __float_as_uint(po[2 * c + 1]);
                        uy += 0x7fffu + ((uy >> 16) & 1u);
                        pk[c] = (ux >> 16) | (uy & 0xffff0000u);
                    }
                    unsigned* op = (unsigned*)outp + ((size_t)gi * MROWS + m) * 64 + jg * 4;
                    *(uint4*)op = make_uint4(pk[0], pk[1], pk[2], pk[3]);
                }
            }
        }
    }
}

// ---------------------------------------------------------------------------
__global__ __launch_bounds__(256) void combine_kernel(
    const unsigned short* __restrict__ opart,
    const float* __restrict__ gbuf, float* __restrict__ ocomb)
{
    size_t idx = (size_t)blockIdx.x * 256 + threadIdx.x;
    float s = 0.f;
#pragma unroll
    for (int gi = 0; gi < GG; ++gi) {
        unsigned u = opart[(size_t)gi * MROWS * CC + idx];
        s += __uint_as_float(u << 16);
    }
    ocomb[idx] = s * gbuf[idx];
}

__global__ __launch_bounds__(256) void gate_kernel(
    float* __restrict__ ocomb, const float* __restrict__ gbuf)
{
    size_t idx = (size_t)blockIdx.x * 256 + threadIdx.x;
    ocomb[idx] *= gbuf[idx];
}

// ---------------------------------------------------------------------------
extern "C" void kernel_launch(void* const* d_in, const int* in_sizes, int n_in,
                              void* d_out, int out_size, void* d_ws, size_t ws_size,
                              hipStream_t stream)
{
    const float* x  = (const float*)d_in[0];
    const float* Wq = (const float*)d_in[1];
    const float* bq = (const float*)d_in[2];
    const float* Wk = (const float*)d_in[3];
    const float* bk = (const float*)d_in[4];
    const float* Wv = (const float*)d_in[5];
    const float* bv = (const float*)d_in[6];
    const float* Wa = (const float*)d_in[7];
    const float* ba = (const float*)d_in[8];
    const float* Wb = (const float*)d_in[9];
    const float* bb = (const float*)d_in[10];
    const float* Wg = (const float*)d_in[11];
    const float* bg = (const float*)d_in[12];
    const float* Wo = (const float*)d_in[13];
    const float* bo = (const float*)d_in[14];
    float* out = (float*)d_out;

    float* ws = (float*)d_ws;
    size_t off = 0;
    float* Wcat    = ws + off; off += (size_t)DIMK * NPROJ;
    float* biascat = ws + off; off += NPROJ;
    float* Y       = ws + off; off += (size_t)MROWS * YSTR;
    float* knorm   = ws + off; off += (size_t)MROWS * CC;
    float* gbuf    = ws + off; off += (size_t)MROWS * CC;
    float* qvpack  = ws + off; off += (size_t)MB * GG * TT * 16;
    float* abpack  = ws + off; off += (size_t)MB * TT * 2;
    float* ocomb   = ws + off; off += (size_t)MROWS * CC;
    unsigned short* opart = (unsigned short*)(ws + off);
    size_t need_big = (off + (size_t)GG * MROWS * CC / 2) * sizeof(float);
    bool big = ws_size >= need_big;

    hipLaunchKernelGGL(pack_w, dim3((DIMK * NPROJ + 255) / 256), dim3(256), 0, stream,
                       Wq, Wk, Wv, Wg, Wa, Wb, Wcat);
    hipLaunchKernelGGL(pack_bias, dim3(1), dim3(NPROJ), 0, stream,
                       bq, bk, bv, bg, ba, bb, biascat);
    hipLaunchKernelGGL(sgemm_bias, dim3(NPROJ / 64, MROWS / 128), dim3(256), 0, stream,
                       x, Wcat, biascat, Y, MROWS, NPROJ, DIMK);
    hipLaunchKernelGGL(postproj_kernel, dim3(MROWS), dim3(64), 0, stream,
                       Y, knorm, gbuf, (float4*)qvpack, (float2*)abpack);
    if (big) {
        hipLaunchKernelGGL((scan_kernel<false>), dim3(MB * GG), dim3(64), 0, stream,
                           knorm, (const float4*)qvpack, (const float2*)abpack, (void*)opart);
        hipLaunchKernelGGL(combine_kernel, dim3(MROWS * CC / 256), dim3(256), 0, stream,
                           opart, gbuf, ocomb);
    } else {
        hipMemsetAsync(ocomb, 0, (size_t)MROWS * CC * sizeof(float), stream);
        hipLaunchKernelGGL((scan_kernel<true>), dim3(MB * GG), dim3(64), 0, stream,
                           knorm, (const float4*)qvpack, (const float2*)abpack, (void*)ocomb);
        hipLaunchKernelGGL(gate_kernel, dim3(MROWS * CC / 256), dim3(256), 0, stream,
                           ocomb, gbuf);
    }
    hipLaunchKernelGGL(sgemm_bias, dim3(DIMK / 64, MROWS / 128), dim3(256), 0, stream,
                       ocomb, Wo, bo, out, MROWS, DIMK, CC);
}

// Round 4
// 1384.305 us; speedup vs baseline: 1.0938x; 1.0938x over previous
//
#include <hip/hip_runtime.h>
#include <hip/hip_bf16.h>
#include <cstdint>

#define MB 8
#define TT 2048
#define DIMK 1024
#define CC 128
#define GG 16
#define MROWS (MB*TT)   /* 16384 */
#define NPROJ 576
#define YSTR 576

// ---------------------------------------------------------------------------
__global__ void pack_w(const float* __restrict__ Wq, const float* __restrict__ Wk,
                       const float* __restrict__ Wv, const float* __restrict__ Wg,
                       const float* __restrict__ Wa, const float* __restrict__ Wb,
                       float* __restrict__ Wcat)
{
    int idx = blockIdx.x * 256 + threadIdx.x;
    if (idx >= DIMK * NPROJ) return;
    int k = idx / NPROJ, n = idx % NPROJ;
    float v = 0.f;
    if      (n < 128) v = Wq[k * 128 + n];
    else if (n < 256) v = Wk[k * 128 + (n - 128)];
    else if (n < 384) v = Wv[k * 128 + (n - 256)];
    else if (n < 512) v = Wg[k * 128 + (n - 384)];
    else if (n == 512) v = Wa[k];
    else if (n == 513) v = Wb[k];
    Wcat[idx] = v;
}

__global__ void pack_bias(const float* __restrict__ bq, const float* __restrict__ bk,
                          const float* __restrict__ bv, const float* __restrict__ bg,
                          const float* __restrict__ ba, const float* __restrict__ bb,
                          float* __restrict__ biascat)
{
    int n = threadIdx.x;
    if (n >= NPROJ) return;
    float v = 0.f;
    if      (n < 128) v = bq[n];
    else if (n < 256) v = bk[n - 128];
    else if (n < 384) v = bv[n - 256];
    else if (n < 512) v = bg[n - 384];
    else if (n == 512) v = ba[0];
    else if (n == 513) v = bb[0];
    biascat[n] = v;
}

// ---------------------------------------------------------------------------
// Tiled fp32 SGEMM: C[M][N] = A[M][K] @ B[K][N] + bias[N]
// ---------------------------------------------------------------------------
__global__ __launch_bounds__(256) void sgemm_bias(
    const float* __restrict__ A, const float* __restrict__ Bm,
    const float* __restrict__ bias, float* __restrict__ Cm,
    int M, int N, int K)
{
    __shared__ float As[16][128];
    __shared__ float Bs[16][64];
    int tid = threadIdx.x;
    int bm = blockIdx.y * 128;
    int bn = blockIdx.x * 64;
    int tx = tid & 15, ty = tid >> 4;
    float acc[8][4];
#pragma unroll
    for (int u = 0; u < 8; u++)
#pragma unroll
        for (int w = 0; w < 4; w++) acc[u][w] = 0.f;

    for (int kk = 0; kk < K; kk += 16) {
#pragma unroll
        for (int j = 0; j < 2; j++) {
            int fid = tid * 2 + j;
            int row = fid >> 2, kq = fid & 3;
            const float4 av = *(const float4*)(A + (size_t)(bm + row) * K + kk + kq * 4);
            As[kq * 4 + 0][row] = av.x;
            As[kq * 4 + 1][row] = av.y;
            As[kq * 4 + 2][row] = av.z;
            As[kq * 4 + 3][row] = av.w;
        }
        {
            int krow = tid >> 4, c4 = tid & 15;
            const float4 bv = *(const float4*)(Bm + (size_t)(kk + krow) * N + bn + c4 * 4);
            *(float4*)&Bs[krow][c4 * 4] = bv;
        }
        __syncthreads();
#pragma unroll
        for (int kc = 0; kc < 16; kc++) {
            float4 a0 = *(const float4*)&As[kc][ty * 8];
            float4 a1 = *(const float4*)&As[kc][ty * 8 + 4];
            float4 bv = *(const float4*)&Bs[kc][tx * 4];
            float av[8] = {a0.x, a0.y, a0.z, a0.w, a1.x, a1.y, a1.z, a1.w};
            float bw[4] = {bv.x, bv.y, bv.z, bv.w};
#pragma unroll
            for (int u = 0; u < 8; u++)
#pragma unroll
                for (int w = 0; w < 4; w++)
                    acc[u][w] += av[u] * bw[w];
        }
        __syncthreads();
    }
    float4 b4 = *(const float4*)(bias + bn + tx * 4);
#pragma unroll
    for (int u = 0; u < 8; u++) {
        float4 r = make_float4(acc[u][0] + b4.x, acc[u][1] + b4.y,
                               acc[u][2] + b4.z, acc[u][3] + b4.w);
        *(float4*)(Cm + (size_t)(bm + ty * 8 + u) * N + bn + tx * 4) = r;
    }
}

// ---------------------------------------------------------------------------
// Post-projection: k row-normalize, sigmoid(g), qv broadcast-pack per
// (block,row,t) as float2, (alpha,beta) as float2. One wave per row m.
// ---------------------------------------------------------------------------
__global__ __launch_bounds__(64) void postproj_kernel(
    const float* __restrict__ Y, float* __restrict__ knorm,
    float* __restrict__ gbuf, float2* __restrict__ qv2,
    float2* __restrict__ abpack)
{
    int m = blockIdx.x;
    int lane = threadIdx.x;
    int b = m >> 11, t = m & (TT - 1);
    const float* yr = Y + (size_t)m * YSTR;
    float k0 = yr[128 + lane], k1 = yr[192 + lane];
    float ss = k0 * k0 + k1 * k1;
#pragma unroll
    for (int mask = 1; mask < 64; mask <<= 1) ss += __shfl_xor(ss, mask);
    float inv = 1.0f / fmaxf(sqrtf(ss), 1e-12f);
    knorm[(size_t)m * CC + lane]      = k0 * inv;
    knorm[(size_t)m * CC + 64 + lane] = k1 * inv;
    float g0 = yr[384 + lane], g1 = yr[448 + lane];
    gbuf[(size_t)m * CC + lane]      = 1.f / (1.f + expf(-g0));
    gbuf[(size_t)m * CC + 64 + lane] = 1.f / (1.f + expf(-g1));
    // qv2[(b*16+gi)*TT + t][rg] = (q_i, v_i), i = gi*8+rg
    {
        int i = lane;
        qv2[((size_t)(b * GG + (i >> 3)) * TT + t) * 8 + (i & 7)] =
            make_float2(yr[i], yr[256 + i]);
        i = lane + 64;
        qv2[((size_t)(b * GG + (i >> 3)) * TT + t) * 8 + (i & 7)] =
            make_float2(yr[i], yr[256 + i]);
    }
    if (lane == 0) {
        float a = 1.f / (1.f + expf(-yr[512]));
        float bb_ = 1.f / (1.f + expf(-yr[513]));
        abpack[(size_t)b * TT + t] = make_float2(a, bb_);
    }
}

// ---------------------------------------------------------------------------
// Cross-lane helpers. DPP quad-perm runs on the VALU pipe (fast); ds_swizzle
// pattern must be an ICE -> template parameter.
// ---------------------------------------------------------------------------
__device__ __forceinline__ float dpp_xor12_add(float p) {
    int i = __float_as_int(p);
    i = __builtin_amdgcn_mov_dpp(i, 0xB1, 0xF, 0xF, true);  // quad_perm [1,0,3,2]
    p += __int_as_float(i);
    i = __float_as_int(p);
    i = __builtin_amdgcn_mov_dpp(i, 0x4E, 0xF, 0xF, true);  // quad_perm [2,3,0,1]
    p += __int_as_float(i);
    return p;
}
template <int PAT>
__device__ __forceinline__ float swz_xor(float p) {
    return __int_as_float(__builtin_amdgcn_ds_swizzle(__float_as_int(p), PAT));
}

// ---------------------------------------------------------------------------
// Sequential scan. Grid = MB*GG single-wave blocks; block (b,gi) owns rows
// [gi*8, gi*8+8). Lane layout: cg=lane&7 -> cols [cg*16,cg*16+16),
// rg=lane>>3 -> row gi*8+rg. State 16 f32/lane.
// ---------------------------------------------------------------------------
#define PFD 4

template <bool ATOMIC>
__global__ __launch_bounds__(64) void scan_kernel(
    const float* __restrict__ knorm, const float2* __restrict__ qv2,
    const float2* __restrict__ abpack, void* __restrict__ outp)
{
    int blk = blockIdx.x;
    int b = blk >> 4;
    int gi = blk & 15;
    int lane = threadIdx.x;
    int cg = lane & 7, rg = lane >> 3;
    float s[16];
#pragma unroll
    for (int c = 0; c < 16; c++) s[c] = 0.f;
    size_t mbase = (size_t)b * TT;

    const float*  knb = knorm + mbase * CC + cg * 16;
    const float2* qvb = qv2 + (size_t)blk * TT * 8 + rg;
    const float2* abb = abpack + mbase;

    float4 kB[PFD][4];
    float2 qvB[PFD], abB[PFD];
#pragma unroll
    for (int u = 0; u < PFD; u++) {
#pragma unroll
        for (int j = 0; j < 4; j++)
            kB[u][j] = *(const float4*)(knb + (size_t)u * CC + j * 4);
        qvB[u] = qvb[(size_t)u * 8];
        abB[u] = abb[u];
    }

    for (int t = 0; t < TT; t += PFD) {
#pragma unroll
        for (int u = 0; u < PFD; u++) {
            float k[16];
#pragma unroll
            for (int j = 0; j < 4; j++) {
                k[j * 4 + 0] = kB[u][j].x; k[j * 4 + 1] = kB[u][j].y;
                k[j * 4 + 2] = kB[u][j].z; k[j * 4 + 3] = kB[u][j].w;
            }
            float2 qv = qvB[u], ab = abB[u];
            int tp = t + u + PFD;
            if (tp < TT) {
#pragma unroll
                for (int j = 0; j < 4; j++)
                    kB[u][j] = *(const float4*)(knb + (size_t)tp * CC + j * 4);
                qvB[u] = qvb[(size_t)tp * 8];
                abB[u] = abb[tp];
            }
            float at = ab.x, bt = ab.y, q = qv.x, v = qv.y;
            // dot: p = s . k  (tree)
            float e[8];
#pragma unroll
            for (int c = 0; c < 8; c++)
                e[c] = fmaf(s[2 * c], k[2 * c], s[2 * c + 1] * k[2 * c + 1]);
            float p = ((e[0] + e[1]) + (e[2] + e[3])) + ((e[4] + e[5]) + (e[6] + e[7]));
            // reduce over 8 cg lanes: xor1,2 (DPP) + xor4 (swizzle)
            p = dpp_xor12_add(p);
            p += swz_xor<0x101F>(p);
            float cr = bt * (v - at * p);
            float po[16];
#pragma unroll
            for (int c = 0; c < 16; c++) {
                s[c] = at * s[c] + cr * k[c];
                po[c] = q * s[c];
            }
            // split-butterfly reduce over rg (xor8, xor16 via swizzle; xor32 via shfl)
            float r8[8];
#pragma unroll
            for (int c = 0; c < 8; c++) {
                float send = (rg & 1) ? po[c] : po[c + 8];
                float keep = (rg & 1) ? po[c + 8] : po[c];
                r8[c] = keep + swz_xor<0x201F>(send);
            }
            float r4[4];
#pragma unroll
            for (int c = 0; c < 4; c++) {
                float send = (rg & 2) ? r8[c] : r8[c + 4];
                float keep = (rg & 2) ? r8[c + 4] : r8[c];
                r4[c] = keep + swz_xor<0x401F>(send);
            }
            float r2[2];
#pragma unroll
            for (int c = 0; c < 2; c++) {
                float send = (rg & 4) ? r4[c] : r4[c + 2];
                float keep = (rg & 4) ? r4[c + 2] : r4[c];
                r2[c] = keep + __shfl_xor(send, 32);
            }
            int colbase = cg * 16 + (rg & 1) * 8 + ((rg >> 1) & 1) * 4 + ((rg >> 2) & 1) * 2;
            size_t m = mbase + t + u;
            if (ATOMIC) {
                float* op = (float*)outp + m * CC + colbase;
                atomicAdd(op, r2[0]);
                atomicAdd(op + 1, r2[1]);
            } else {
                unsigned ux = __float_as_uint(r2[0]);
                ux += 0x7fffu + ((ux >> 16) & 1u);
                unsigned uy = __float_as_uint(r2[1]);
                uy += 0x7fffu + ((uy >> 16) & 1u);
                unsigned pk = (ux >> 16) | (uy & 0xffff0000u);
                ((unsigned*)outp)[((size_t)gi * MROWS + m) * 64 + (colbase >> 1)] = pk;
            }
        }
    }
}

// ---------------------------------------------------------------------------
__global__ __launch_bounds__(256) void combine_kernel(
    const unsigned short* __restrict__ opart,
    const float* __restrict__ gbuf, float* __restrict__ ocomb)
{
    size_t idx = (size_t)blockIdx.x * 256 + threadIdx.x;
    float s = 0.f;
#pragma unroll
    for (int gi = 0; gi < GG; ++gi) {
        unsigned u = opart[(size_t)gi * MROWS * CC + idx];
        s += __uint_as_float(u << 16);
    }
    ocomb[idx] = s * gbuf[idx];
}

__global__ __launch_bounds__(256) void gate_kernel(
    float* __restrict__ ocomb, const float* __restrict__ gbuf)
{
    size_t idx = (size_t)blockIdx.x * 256 + threadIdx.x;
    ocomb[idx] *= gbuf[idx];
}

// ---------------------------------------------------------------------------
extern "C" void kernel_launch(void* const* d_in, const int* in_sizes, int n_in,
                              void* d_out, int out_size, void* d_ws, size_t ws_size,
                              hipStream_t stream)
{
    const float* x  = (const float*)d_in[0];
    const float* Wq = (const float*)d_in[1];
    const float* bq = (const float*)d_in[2];
    const float* Wk = (const float*)d_in[3];
    const float* bk = (const float*)d_in[4];
    const float* Wv = (const float*)d_in[5];
    const float* bv = (const float*)d_in[6];
    const float* Wa = (const float*)d_in[7];
    const float* ba = (const float*)d_in[8];
    const float* Wb = (const float*)d_in[9];
    const float* bb = (const float*)d_in[10];
    const float* Wg = (const float*)d_in[11];
    const float* bg = (const float*)d_in[12];
    const float* Wo = (const float*)d_in[13];
    const float* bo = (const float*)d_in[14];
    float* out = (float*)d_out;

    float* ws = (float*)d_ws;
    size_t off = 0;
    float* Wcat    = ws + off; off += (size_t)DIMK * NPROJ;
    float* biascat = ws + off; off += NPROJ;
    float* Y       = ws + off; off += (size_t)MROWS * YSTR;
    float* knorm   = ws + off; off += (size_t)MROWS * CC;
    float* gbuf    = ws + off; off += (size_t)MROWS * CC;
    float* qv2     = ws + off; off += (size_t)MB * GG * TT * 16;
    float* abpack  = ws + off; off += (size_t)MB * TT * 2;
    float* ocomb   = ws + off; off += (size_t)MROWS * CC;
    unsigned short* opart = (unsigned short*)(ws + off);
    size_t need_big = (off + (size_t)GG * MROWS * CC / 2) * sizeof(float);
    bool big = ws_size >= need_big;

    hipLaunchKernelGGL(pack_w, dim3((DIMK * NPROJ + 255) / 256), dim3(256), 0, stream,
                       Wq, Wk, Wv, Wg, Wa, Wb, Wcat);
    hipLaunchKernelGGL(pack_bias, dim3(1), dim3(NPROJ), 0, stream,
                       bq, bk, bv, bg, ba, bb, biascat);
    hipLaunchKernelGGL(sgemm_bias, dim3(NPROJ / 64, MROWS / 128), dim3(256), 0, stream,
                       x, Wcat, biascat, Y, MROWS, NPROJ, DIMK);
    hipLaunchKernelGGL(postproj_kernel, dim3(MROWS), dim3(64), 0, stream,
                       Y, knorm, gbuf, (float2*)qv2, (float2*)abpack);
    if (big) {
        hipLaunchKernelGGL((scan_kernel<false>), dim3(MB * GG), dim3(64), 0, stream,
                           knorm, (const float2*)qv2, (const float2*)abpack, (void*)opart);
        hipLaunchKernelGGL(combine_kernel, dim3(MROWS * CC / 256), dim3(256), 0, stream,
                           opart, gbuf, ocomb);
    } else {
        (void)hipMemsetAsync(ocomb, 0, (size_t)MROWS * CC * sizeof(float), stream);
        hipLaunchKernelGGL((scan_kernel<true>), dim3(MB * GG), dim3(64), 0, stream,
                           knorm, (const float2*)qv2, (const float2*)abpack, (void*)ocomb);
        hipLaunchKernelGGL(gate_kernel, dim3(MROWS * CC / 256), dim3(256), 0, stream,
                           ocomb, gbuf);
    }
    hipLaunchKernelGGL(sgemm_bias, dim3(DIMK / 64, MROWS / 128), dim3(256), 0, stream,
                       ocomb, Wo, bo, out, MROWS, DIMK, CC);
}

// Round 5
// 1334.345 us; speedup vs baseline: 1.1347x; 1.0374x over previous
//
#include <hip/hip_runtime.h>
#include <hip/hip_bf16.h>
#include <hip/hip_fp16.h>
#include <cstdint>

#define MB 8
#define TT 2048
#define DIMK 1024
#define CC 128
#define GG 16
#define MROWS (MB*TT)   /* 16384 */
#define NPROJ 576
#define YSTR 576

// ---------------------------------------------------------------------------
__global__ void pack_w(const float* __restrict__ Wq, const float* __restrict__ Wk,
                       const float* __restrict__ Wv, const float* __restrict__ Wg,
                       const float* __restrict__ Wa, const float* __restrict__ Wb,
                       float* __restrict__ Wcat)
{
    int idx = blockIdx.x * 256 + threadIdx.x;
    if (idx >= DIMK * NPROJ) return;
    int k = idx / NPROJ, n = idx % NPROJ;
    float v = 0.f;
    if      (n < 128) v = Wq[k * 128 + n];
    else if (n < 256) v = Wk[k * 128 + (n - 128)];
    else if (n < 384) v = Wv[k * 128 + (n - 256)];
    else if (n < 512) v = Wg[k * 128 + (n - 384)];
    else if (n == 512) v = Wa[k];
    else if (n == 513) v = Wb[k];
    Wcat[idx] = v;
}

__global__ void pack_bias(const float* __restrict__ bq, const float* __restrict__ bk,
                          const float* __restrict__ bv, const float* __restrict__ bg,
                          const float* __restrict__ ba, const float* __restrict__ bb,
                          float* __restrict__ biascat)
{
    int n = threadIdx.x;
    if (n >= NPROJ) return;
    float v = 0.f;
    if      (n < 128) v = bq[n];
    else if (n < 256) v = bk[n - 128];
    else if (n < 384) v = bv[n - 256];
    else if (n < 512) v = bg[n - 384];
    else if (n == 512) v = ba[0];
    else if (n == 513) v = bb[0];
    biascat[n] = v;
}

// ---------------------------------------------------------------------------
// Tiled fp32 SGEMM: C[M][N] = A[M][K] @ B[K][N] + bias[N]
// ---------------------------------------------------------------------------
__global__ __launch_bounds__(256) void sgemm_bias(
    const float* __restrict__ A, const float* __restrict__ Bm,
    const float* __restrict__ bias, float* __restrict__ Cm,
    int M, int N, int K)
{
    __shared__ float As[16][128];
    __shared__ float Bs[16][64];
    int tid = threadIdx.x;
    int bm = blockIdx.y * 128;
    int bn = blockIdx.x * 64;
    int tx = tid & 15, ty = tid >> 4;
    float acc[8][4];
#pragma unroll
    for (int u = 0; u < 8; u++)
#pragma unroll
        for (int w = 0; w < 4; w++) acc[u][w] = 0.f;

    for (int kk = 0; kk < K; kk += 16) {
#pragma unroll
        for (int j = 0; j < 2; j++) {
            int fid = tid * 2 + j;
            int row = fid >> 2, kq = fid & 3;
            const float4 av = *(const float4*)(A + (size_t)(bm + row) * K + kk + kq * 4);
            As[kq * 4 + 0][row] = av.x;
            As[kq * 4 + 1][row] = av.y;
            As[kq * 4 + 2][row] = av.z;
            As[kq * 4 + 3][row] = av.w;
        }
        {
            int krow = tid >> 4, c4 = tid & 15;
            const float4 bv = *(const float4*)(Bm + (size_t)(kk + krow) * N + bn + c4 * 4);
            *(float4*)&Bs[krow][c4 * 4] = bv;
        }
        __syncthreads();
#pragma unroll
        for (int kc = 0; kc < 16; kc++) {
            float4 a0 = *(const float4*)&As[kc][ty * 8];
            float4 a1 = *(const float4*)&As[kc][ty * 8 + 4];
            float4 bv = *(const float4*)&Bs[kc][tx * 4];
            float av[8] = {a0.x, a0.y, a0.z, a0.w, a1.x, a1.y, a1.z, a1.w};
            float bw[4] = {bv.x, bv.y, bv.z, bv.w};
#pragma unroll
            for (int u = 0; u < 8; u++)
#pragma unroll
                for (int w = 0; w < 4; w++)
                    acc[u][w] += av[u] * bw[w];
        }
        __syncthreads();
    }
    float4 b4 = *(const float4*)(bias + bn + tx * 4);
#pragma unroll
    for (int u = 0; u < 8; u++) {
        float4 r = make_float4(acc[u][0] + b4.x, acc[u][1] + b4.y,
                               acc[u][2] + b4.z, acc[u][3] + b4.w);
        *(float4*)(Cm + (size_t)(bm + ty * 8 + u) * N + bn + tx * 4) = r;
    }
}

// ---------------------------------------------------------------------------
// Post-projection: k row-normalize, sigmoid(g), qv broadcast-pack per
// (block,row,t) as float2, (alpha,beta) as float2. One wave per row m.
// ---------------------------------------------------------------------------
__global__ __launch_bounds__(64) void postproj_kernel(
    const float* __restrict__ Y, float* __restrict__ knorm,
    float* __restrict__ gbuf, float2* __restrict__ qv2,
    float2* __restrict__ abpack)
{
    int m = blockIdx.x;
    int lane = threadIdx.x;
    int b = m >> 11, t = m & (TT - 1);
    const float* yr = Y + (size_t)m * YSTR;
    float k0 = yr[128 + lane], k1 = yr[192 + lane];
    float ss = k0 * k0 + k1 * k1;
#pragma unroll
    for (int mask = 1; mask < 64; mask <<= 1) ss += __shfl_xor(ss, mask);
    float inv = 1.0f / fmaxf(sqrtf(ss), 1e-12f);
    knorm[(size_t)m * CC + lane]      = k0 * inv;
    knorm[(size_t)m * CC + 64 + lane] = k1 * inv;
    float g0 = yr[384 + lane], g1 = yr[448 + lane];
    gbuf[(size_t)m * CC + lane]      = 1.f / (1.f + expf(-g0));
    gbuf[(size_t)m * CC + 64 + lane] = 1.f / (1.f + expf(-g1));
    // qv2[(b*16+gi)*TT + t][rg] = (q_i, v_i), i = gi*8+rg
    {
        int i = lane;
        qv2[((size_t)(b * GG + (i >> 3)) * TT + t) * 8 + (i & 7)] =
            make_float2(yr[i], yr[256 + i]);
        i = lane + 64;
        qv2[((size_t)(b * GG + (i >> 3)) * TT + t) * 8 + (i & 7)] =
            make_float2(yr[i], yr[256 + i]);
    }
    if (lane == 0) {
        float a = 1.f / (1.f + expf(-yr[512]));
        float bb_ = 1.f / (1.f + expf(-yr[513]));
        abpack[(size_t)b * TT + t] = make_float2(a, bb_);
    }
}

// ---------------------------------------------------------------------------
// Cross-lane helpers.
// ---------------------------------------------------------------------------
__device__ __forceinline__ float dpp_add_xor1(float p) {
    int i = __builtin_amdgcn_mov_dpp(__float_as_int(p), 0xB1, 0xF, 0xF, true);
    return p + __int_as_float(i);
}
__device__ __forceinline__ float dpp_add_xor2(float p) {
    int i = __builtin_amdgcn_mov_dpp(__float_as_int(p), 0x4E, 0xF, 0xF, true);
    return p + __int_as_float(i);
}
__device__ __forceinline__ float dpp_add_xor8(float p) {
    // row_ror:8 within 16-lane row == lane^8
    int i = __builtin_amdgcn_mov_dpp(__float_as_int(p), 0x128, 0xF, 0xF, true);
    return p + __int_as_float(i);
}
__device__ __forceinline__ int h2i(__half2 h) { int i; __builtin_memcpy(&i, &h, 4); return i; }
__device__ __forceinline__ __half2 i2h(int i) { __half2 h; __builtin_memcpy(&h, &i, 4); return h; }
template <int PAT>
__device__ __forceinline__ __half2 swz_h2(__half2 x) {
    return i2h(__builtin_amdgcn_ds_swizzle(h2i(x), PAT));
}

// ---------------------------------------------------------------------------
// Sequential scan. Grid = MB*GG single-wave blocks; block (b,gi) owns rows
// [gi*8, gi*8+8). Lane layout: cg = bits{0,1,3} -> cols [cg*16,cg*16+16),
// rg = bits{2,4,5} -> row gi*8+rg. State 16 f32/lane.
// Dot reduction over cg lanes: xor1,xor2 (quad_perm DPP) + xor8 (row_ror:8
// DPP) -- zero LDS on the recurrence critical path.
// po reduction over rg lanes: batched every PFD steps, f16x2-packed
// split-butterfly (xor4, xor16 swizzles + xor32 shfl), level-grouped so LDS
// latency is amortized across the batch.
// ---------------------------------------------------------------------------
#define PFD 4

template <bool ATOMIC>
__global__ __launch_bounds__(64) void scan_kernel(
    const float* __restrict__ knorm, const float2* __restrict__ qv2,
    const float2* __restrict__ abpack, void* __restrict__ outp)
{
    int blk = blockIdx.x;
    int b = blk >> 4;
    int gi = blk & 15;
    int lane = threadIdx.x;
    int cg  = (lane & 3) | ((lane >> 1) & 4);   // bits 0,1,3
    int rb0 = (lane >> 2) & 1;                  // bit 2
    int rb1 = (lane >> 4) & 1;                  // bit 4
    int rb2 = (lane >> 5) & 1;                  // bit 5
    int rg  = rb0 | (rb1 << 1) | (rb2 << 2);
    float s[16];
#pragma unroll
    for (int c = 0; c < 16; c++) s[c] = 0.f;
    size_t mbase = (size_t)b * TT;

    const float*  knb = knorm + mbase * CC + cg * 16;
    const float2* qvb = qv2 + (size_t)blk * TT * 8 + rg;
    const float2* abb = abpack + mbase;

    float4 kB[PFD][4];
    float2 qvB[PFD], abB[PFD];
#pragma unroll
    for (int u = 0; u < PFD; u++) {
#pragma unroll
        for (int j = 0; j < 4; j++)
            kB[u][j] = *(const float4*)(knb + (size_t)u * CC + j * 4);
        qvB[u] = qvb[(size_t)u * 8];
        abB[u] = abb[u];
    }

    int bperm_addr = (lane ^ 32) << 2;   // for xor32 via ds_bpermute

    for (int t = 0; t < TT; t += PFD) {
        __half2 pb[PFD][8];
#pragma unroll
        for (int u = 0; u < PFD; u++) {
            float k[16];
#pragma unroll
            for (int j = 0; j < 4; j++) {
                k[j * 4 + 0] = kB[u][j].x; k[j * 4 + 1] = kB[u][j].y;
                k[j * 4 + 2] = kB[u][j].z; k[j * 4 + 3] = kB[u][j].w;
            }
            float2 qv = qvB[u], ab = abB[u];
            int tp = t + u + PFD;
            if (tp < TT) {
#pragma unroll
                for (int j = 0; j < 4; j++)
                    kB[u][j] = *(const float4*)(knb + (size_t)tp * CC + j * 4);
                qvB[u] = qvb[(size_t)tp * 8];
                abB[u] = abb[tp];
            }
            float at = ab.x, bt = ab.y, q = qv.x, v = qv.y;
            // dot p = s.k (in-lane tree, then 3 DPP butterflies)
            float e[8];
#pragma unroll
            for (int c = 0; c < 8; c++)
                e[c] = fmaf(s[2 * c], k[2 * c], s[2 * c + 1] * k[2 * c + 1]);
            float p = ((e[0] + e[1]) + (e[2] + e[3])) + ((e[4] + e[5]) + (e[6] + e[7]));
            p = dpp_add_xor1(p);
            p = dpp_add_xor2(p);
            p = dpp_add_xor8(p);
            float cr = bt * (v - at * p);
            float po[16];
#pragma unroll
            for (int c = 0; c < 16; c++) {
                s[c] = at * s[c] + cr * k[c];
                po[c] = q * s[c];
            }
#pragma unroll
            for (int j = 0; j < 8; j++)
                pb[u][j] = __float22half2_rn(make_float2(po[2 * j], po[2 * j + 1]));
        }
        // ---- batched po reduction over rg lanes (level-grouped) ----
        __half2 r1[PFD][4];
#pragma unroll
        for (int u = 0; u < PFD; u++)
#pragma unroll
            for (int j = 0; j < 4; j++) {
                __half2 keep = rb0 ? pb[u][j + 4] : pb[u][j];
                __half2 send = rb0 ? pb[u][j] : pb[u][j + 4];
                r1[u][j] = __hadd2(keep, swz_h2<0x101F>(send));   // xor4
            }
        __half2 r2[PFD][2];
#pragma unroll
        for (int u = 0; u < PFD; u++)
#pragma unroll
            for (int j = 0; j < 2; j++) {
                __half2 keep = rb1 ? r1[u][j + 2] : r1[u][j];
                __half2 send = rb1 ? r1[u][j] : r1[u][j + 2];
                r2[u][j] = __hadd2(keep, swz_h2<0x401F>(send));   // xor16
            }
        __half2 r3[PFD];
#pragma unroll
        for (int u = 0; u < PFD; u++) {
            __half2 keep = rb2 ? r2[u][1] : r2[u][0];
            __half2 send = rb2 ? r2[u][0] : r2[u][1];
            int sv = __builtin_amdgcn_ds_bpermute(bperm_addr, h2i(send)); // xor32
            r3[u] = __hadd2(keep, i2h(sv));
        }
        int cp = cg * 8 + rb0 * 4 + rb1 * 2 + rb2;   // col-pair index 0..63
#pragma unroll
        for (int u = 0; u < PFD; u++) {
            size_t m = mbase + t + u;
            if (ATOMIC) {
                float2 f = __half22float2(r3[u]);
                float* op = (float*)outp + m * CC + cp * 2;
                atomicAdd(op, f.x);
                atomicAdd(op + 1, f.y);
            } else {
                ((unsigned*)outp)[((size_t)gi * MROWS + m) * 64 + cp] =
                    (unsigned)h2i(r3[u]);
            }
        }
    }
}

// ---------------------------------------------------------------------------
// Combine f16x2 partials over G groups, apply gate. One dword = 2 cols.
// ---------------------------------------------------------------------------
__global__ __launch_bounds__(256) void combine_kernel(
    const unsigned* __restrict__ opart,
    const float* __restrict__ gbuf, float* __restrict__ ocomb)
{
    size_t idx = (size_t)blockIdx.x * 256 + threadIdx.x;  // < MROWS*64
    float sx = 0.f, sy = 0.f;
#pragma unroll
    for (int gi = 0; gi < GG; ++gi) {
        __half2 h = i2h((int)opart[(size_t)gi * MROWS * 64 + idx]);
        float2 f = __half22float2(h);
        sx += f.x; sy += f.y;
    }
    float2 g = *(const float2*)(gbuf + idx * 2);
    *(float2*)(ocomb + idx * 2) = make_float2(sx * g.x, sy * g.y);
}

__global__ __launch_bounds__(256) void gate_kernel(
    float* __restrict__ ocomb, const float* __restrict__ gbuf)
{
    size_t idx = (size_t)blockIdx.x * 256 + threadIdx.x;
    ocomb[idx] *= gbuf[idx];
}

// ---------------------------------------------------------------------------
extern "C" void kernel_launch(void* const* d_in, const int* in_sizes, int n_in,
                              void* d_out, int out_size, void* d_ws, size_t ws_size,
                              hipStream_t stream)
{
    const float* x  = (const float*)d_in[0];
    const float* Wq = (const float*)d_in[1];
    const float* bq = (const float*)d_in[2];
    const float* Wk = (const float*)d_in[3];
    const float* bk = (const float*)d_in[4];
    const float* Wv = (const float*)d_in[5];
    const float* bv = (const float*)d_in[6];
    const float* Wa = (const float*)d_in[7];
    const float* ba = (const float*)d_in[8];
    const float* Wb = (const float*)d_in[9];
    const float* bb = (const float*)d_in[10];
    const float* Wg = (const float*)d_in[11];
    const float* bg = (const float*)d_in[12];
    const float* Wo = (const float*)d_in[13];
    const float* bo = (const float*)d_in[14];
    float* out = (float*)d_out;

    float* ws = (float*)d_ws;
    size_t off = 0;
    float* Wcat    = ws + off; off += (size_t)DIMK * NPROJ;
    float* biascat = ws + off; off += NPROJ;
    float* Y       = ws + off; off += (size_t)MROWS * YSTR;
    float* knorm   = ws + off; off += (size_t)MROWS * CC;
    float* gbuf    = ws + off; off += (size_t)MROWS * CC;
    float* qv2     = ws + off; off += (size_t)MB * GG * TT * 16;
    float* abpack  = ws + off; off += (size_t)MB * TT * 2;
    float* ocomb   = ws + off; off += (size_t)MROWS * CC;
    unsigned* opart = (unsigned*)(ws + off);
    size_t need_big = (off + (size_t)GG * MROWS * CC / 2) * sizeof(float);
    bool big = ws_size >= need_big;

    hipLaunchKernelGGL(pack_w, dim3((DIMK * NPROJ + 255) / 256), dim3(256), 0, stream,
                       Wq, Wk, Wv, Wg, Wa, Wb, Wcat);
    hipLaunchKernelGGL(pack_bias, dim3(1), dim3(NPROJ), 0, stream,
                       bq, bk, bv, bg, ba, bb, biascat);
    hipLaunchKernelGGL(sgemm_bias, dim3(NPROJ / 64, MROWS / 128), dim3(256), 0, stream,
                       x, Wcat, biascat, Y, MROWS, NPROJ, DIMK);
    hipLaunchKernelGGL(postproj_kernel, dim3(MROWS), dim3(64), 0, stream,
                       Y, knorm, gbuf, (float2*)qv2, (float2*)abpack);
    if (big) {
        hipLaunchKernelGGL((scan_kernel<false>), dim3(MB * GG), dim3(64), 0, stream,
                           knorm, (const float2*)qv2, (const float2*)abpack, (void*)opart);
        hipLaunchKernelGGL(combine_kernel, dim3(MROWS * 64 / 256), dim3(256), 0, stream,
                           opart, gbuf, ocomb);
    } else {
        (void)hipMemsetAsync(ocomb, 0, (size_t)MROWS * CC * sizeof(float), stream);
        hipLaunchKernelGGL((scan_kernel<true>), dim3(MB * GG), dim3(64), 0, stream,
                           knorm, (const float2*)qv2, (const float2*)abpack, (void*)ocomb);
        hipLaunchKernelGGL(gate_kernel, dim3(MROWS * CC / 256), dim3(256), 0, stream,
                           ocomb, gbuf);
    }
    hipLaunchKernelGGL(sgemm_bias, dim3(DIMK / 64, MROWS / 128), dim3(256), 0, stream,
                       ocomb, Wo, bo, out, MROWS, DIMK, CC);
}

// Round 6
// 1176.990 us; speedup vs baseline: 1.2865x; 1.1337x over previous
//
#include <hip/hip_runtime.h>
#include <hip/hip_bf16.h>
#include <hip/hip_fp16.h>
#include <cstdint>

#define MB 8
#define TT 2048
#define DIMK 1024
#define CC 128
#define GG 16
#define MROWS (MB*TT)   /* 16384 */
#define NPROJ 576
#define YSTR 576

// ---------------------------------------------------------------------------
__global__ void pack_w(const float* __restrict__ Wq, const float* __restrict__ Wk,
                       const float* __restrict__ Wv, const float* __restrict__ Wg,
                       const float* __restrict__ Wa, const float* __restrict__ Wb,
                       float* __restrict__ Wcat)
{
    int idx = blockIdx.x * 256 + threadIdx.x;
    if (idx >= DIMK * NPROJ) return;
    int k = idx / NPROJ, n = idx % NPROJ;
    float v = 0.f;
    if      (n < 128) v = Wq[k * 128 + n];
    else if (n < 256) v = Wk[k * 128 + (n - 128)];
    else if (n < 384) v = Wv[k * 128 + (n - 256)];
    else if (n < 512) v = Wg[k * 128 + (n - 384)];
    else if (n == 512) v = Wa[k];
    else if (n == 513) v = Wb[k];
    Wcat[idx] = v;
}

__global__ void pack_bias(const float* __restrict__ bq, const float* __restrict__ bk,
                          const float* __restrict__ bv, const float* __restrict__ bg,
                          const float* __restrict__ ba, const float* __restrict__ bb,
                          float* __restrict__ biascat)
{
    int n = threadIdx.x;
    if (n >= NPROJ) return;
    float v = 0.f;
    if      (n < 128) v = bq[n];
    else if (n < 256) v = bk[n - 128];
    else if (n < 384) v = bv[n - 256];
    else if (n < 512) v = bg[n - 384];
    else if (n == 512) v = ba[0];
    else if (n == 513) v = bb[0];
    biascat[n] = v;
}

// ---------------------------------------------------------------------------
// Tiled fp32 SGEMM: C[M][N] = A[M][K] @ B[K][N] + bias[N]
// ---------------------------------------------------------------------------
__global__ __launch_bounds__(256) void sgemm_bias(
    const float* __restrict__ A, const float* __restrict__ Bm,
    const float* __restrict__ bias, float* __restrict__ Cm,
    int M, int N, int K)
{
    __shared__ float As[16][128];
    __shared__ float Bs[16][64];
    int tid = threadIdx.x;
    int bm = blockIdx.y * 128;
    int bn = blockIdx.x * 64;
    int tx = tid & 15, ty = tid >> 4;
    float acc[8][4];
#pragma unroll
    for (int u = 0; u < 8; u++)
#pragma unroll
        for (int w = 0; w < 4; w++) acc[u][w] = 0.f;

    for (int kk = 0; kk < K; kk += 16) {
#pragma unroll
        for (int j = 0; j < 2; j++) {
            int fid = tid * 2 + j;
            int row = fid >> 2, kq = fid & 3;
            const float4 av = *(const float4*)(A + (size_t)(bm + row) * K + kk + kq * 4);
            As[kq * 4 + 0][row] = av.x;
            As[kq * 4 + 1][row] = av.y;
            As[kq * 4 + 2][row] = av.z;
            As[kq * 4 + 3][row] = av.w;
        }
        {
            int krow = tid >> 4, c4 = tid & 15;
            const float4 bv = *(const float4*)(Bm + (size_t)(kk + krow) * N + bn + c4 * 4);
            *(float4*)&Bs[krow][c4 * 4] = bv;
        }
        __syncthreads();
#pragma unroll
        for (int kc = 0; kc < 16; kc++) {
            float4 a0 = *(const float4*)&As[kc][ty * 8];
            float4 a1 = *(const float4*)&As[kc][ty * 8 + 4];
            float4 bv = *(const float4*)&Bs[kc][tx * 4];
            float av[8] = {a0.x, a0.y, a0.z, a0.w, a1.x, a1.y, a1.z, a1.w};
            float bw[4] = {bv.x, bv.y, bv.z, bv.w};
#pragma unroll
            for (int u = 0; u < 8; u++)
#pragma unroll
                for (int w = 0; w < 4; w++)
                    acc[u][w] += av[u] * bw[w];
        }
        __syncthreads();
    }
    float4 b4 = *(const float4*)(bias + bn + tx * 4);
#pragma unroll
    for (int u = 0; u < 8; u++) {
        float4 r = make_float4(acc[u][0] + b4.x, acc[u][1] + b4.y,
                               acc[u][2] + b4.z, acc[u][3] + b4.w);
        *(float4*)(Cm + (size_t)(bm + ty * 8 + u) * N + bn + tx * 4) = r;
    }
}

// ---------------------------------------------------------------------------
// Post-projection: k row-normalize, sigmoid(g), (q,v,alpha,beta) packed per
// (block,row,t) as float4. One wave per row m.
// ---------------------------------------------------------------------------
__global__ __launch_bounds__(64) void postproj_kernel(
    const float* __restrict__ Y, float* __restrict__ knorm,
    float* __restrict__ gbuf, float4* __restrict__ qvab)
{
    int m = blockIdx.x;
    int lane = threadIdx.x;
    int b = m >> 11, t = m & (TT - 1);
    const float* yr = Y + (size_t)m * YSTR;
    float k0 = yr[128 + lane], k1 = yr[192 + lane];
    float ss = k0 * k0 + k1 * k1;
#pragma unroll
    for (int mask = 1; mask < 64; mask <<= 1) ss += __shfl_xor(ss, mask);
    float inv = 1.0f / fmaxf(sqrtf(ss), 1e-12f);
    knorm[(size_t)m * CC + lane]      = k0 * inv;
    knorm[(size_t)m * CC + 64 + lane] = k1 * inv;
    float g0 = yr[384 + lane], g1 = yr[448 + lane];
    gbuf[(size_t)m * CC + lane]      = 1.f / (1.f + expf(-g0));
    gbuf[(size_t)m * CC + 64 + lane] = 1.f / (1.f + expf(-g1));
    float a  = 1.f / (1.f + expf(-yr[512]));
    float bb = 1.f / (1.f + expf(-yr[513]));
    // qvab[((b*GG+gi)*TT + t)*8 + rg] = (q_i, v_i, a, b), i = gi*8+rg
    {
        int i = lane;
        qvab[((size_t)(b * GG + (i >> 3)) * TT + t) * 8 + (i & 7)] =
            make_float4(yr[i], yr[256 + i], a, bb);
        i = lane + 64;
        qvab[((size_t)(b * GG + (i >> 3)) * TT + t) * 8 + (i & 7)] =
            make_float4(yr[i], yr[256 + i], a, bb);
    }
}

// ---------------------------------------------------------------------------
// Cross-lane helpers (all ICE-pattern).
// ---------------------------------------------------------------------------
__device__ __forceinline__ float dpp_add_xor1(float p) {
    int i = __builtin_amdgcn_mov_dpp(__float_as_int(p), 0xB1, 0xF, 0xF, true);
    return p + __int_as_float(i);
}
__device__ __forceinline__ float dpp_add_xor2(float p) {
    int i = __builtin_amdgcn_mov_dpp(__float_as_int(p), 0x4E, 0xF, 0xF, true);
    return p + __int_as_float(i);
}
__device__ __forceinline__ float dpp_add_mirror7(float p) {
    // row_half_mirror: lane i -> i^7 (within 8). After xor1+xor2, adds the
    // other 4-group's sum -> full reduction over lane bits {0,1,2}.
    int i = __builtin_amdgcn_mov_dpp(__float_as_int(p), 0x141, 0xF, 0xF, true);
    return p + __int_as_float(i);
}
__device__ __forceinline__ int h2i(__half2 h) { int i; __builtin_memcpy(&i, &h, 4); return i; }
__device__ __forceinline__ __half2 i2h(int i) { __half2 h; __builtin_memcpy(&h, &i, 4); return h; }
__device__ __forceinline__ __half2 dpp_xor8_h2(__half2 x) {
    return i2h(__builtin_amdgcn_mov_dpp(h2i(x), 0x128, 0xF, 0xF, true)); // row_ror:8 = lane^8
}
template <int PAT>
__device__ __forceinline__ __half2 swz_h2(__half2 x) {
    return i2h(__builtin_amdgcn_ds_swizzle(h2i(x), PAT));
}
__device__ __forceinline__ float2 f2mul(float2 a, float2 b) {
    return make_float2(a.x * b.x, a.y * b.y);
}
__device__ __forceinline__ float2 f2fma(float2 a, float2 b, float2 c) {
    return make_float2(fmaf(a.x, b.x, c.x), fmaf(a.y, b.y, c.y));
}

// ---------------------------------------------------------------------------
// Sequential scan. Grid = MB*GG single-wave blocks; block (b,gi) owns rows
// [gi*8, gi*8+8). Lane layout: cg=lane&7 -> cols [cg*16,cg*16+16),
// rg=lane>>3 -> row gi*8+rg. State 8 float2/lane.
// Dot reduction over cg (bits 0-2): xor1, xor2 (quad_perm) + i^7
// (row_half_mirror) -- all DPP, zero LDS on the recurrence path.
// po reduction over rg (bits 3-5): xor8 via DPP, xor16 via swizzle, xor32
// via bpermute; batched every PFD steps so only 2 lgkm wait-rounds/batch.
// ---------------------------------------------------------------------------
#define PFD 4

template <bool ATOMIC>
__global__ __launch_bounds__(64) void scan_kernel(
    const float* __restrict__ knorm, const float4* __restrict__ qvab,
    void* __restrict__ outp)
{
    int blk = blockIdx.x;
    int b = blk >> 4;
    int gi = blk & 15;
    int lane = threadIdx.x;
    int cg = lane & 7, rg = lane >> 3;
    int rb0 = rg & 1, rb1 = (rg >> 1) & 1, rb2 = (rg >> 2) & 1;
    float2 s2[8];
#pragma unroll
    for (int c = 0; c < 8; c++) s2[c] = make_float2(0.f, 0.f);
    size_t mbase = (size_t)b * TT;

    const float*  knb = knorm + mbase * CC + cg * 16;
    const float4* qvb = qvab + (size_t)blk * TT * 8 + rg;

    float4 kB[PFD][4];
    float4 qB[PFD];
#pragma unroll
    for (int u = 0; u < PFD; u++) {
#pragma unroll
        for (int j = 0; j < 4; j++)
            kB[u][j] = *(const float4*)(knb + (size_t)u * CC + j * 4);
        qB[u] = qvb[(size_t)u * 8];
    }

    int bperm_addr = (lane ^ 32) << 2;   // xor32 via ds_bpermute

    for (int t = 0; t < TT; t += PFD) {
        __half2 pb[PFD][8];
#pragma unroll
        for (int u = 0; u < PFD; u++) {
            float2 k2[8];
#pragma unroll
            for (int j = 0; j < 4; j++) {
                k2[2 * j]     = make_float2(kB[u][j].x, kB[u][j].y);
                k2[2 * j + 1] = make_float2(kB[u][j].z, kB[u][j].w);
            }
            float4 qv = qB[u];
            int tp = t + u + PFD;
            if (tp < TT) {
#pragma unroll
                for (int j = 0; j < 4; j++)
                    kB[u][j] = *(const float4*)(knb + (size_t)tp * CC + j * 4);
                qB[u] = qvb[(size_t)tp * 8];
            }
            float q = qv.x, v = qv.y, at = qv.z, bt = qv.w;
            // dot p = s.k: two independent pk-fma chains
            float2 a0 = f2mul(s2[0], k2[0]);
            float2 a1 = f2mul(s2[1], k2[1]);
            a0 = f2fma(s2[2], k2[2], a0);
            a1 = f2fma(s2[3], k2[3], a1);
            a0 = f2fma(s2[4], k2[4], a0);
            a1 = f2fma(s2[5], k2[5], a1);
            a0 = f2fma(s2[6], k2[6], a0);
            a1 = f2fma(s2[7], k2[7], a1);
            float p = (a0.x + a1.x) + (a0.y + a1.y);
            p = dpp_add_xor1(p);
            p = dpp_add_xor2(p);
            p = dpp_add_mirror7(p);
            float cr = bt * (v - at * p);
            float2 at2 = make_float2(at, at);
            float2 cr2 = make_float2(cr, cr);
            float2 q2  = make_float2(q, q);
#pragma unroll
            for (int c = 0; c < 8; c++) {
                s2[c] = f2fma(k2[c], cr2, f2mul(s2[c], at2));
                float2 po = f2mul(q2, s2[c]);
                pb[u][c] = __float22half2_rn(po);
            }
        }
        // ---- batched po reduction over rg lanes ----
        // level xor8 (DPP, no LDS)
        __half2 r1[PFD][4];
#pragma unroll
        for (int u = 0; u < PFD; u++)
#pragma unroll
            for (int j = 0; j < 4; j++) {
                __half2 keep = rb0 ? pb[u][j + 4] : pb[u][j];
                __half2 send = rb0 ? pb[u][j] : pb[u][j + 4];
                r1[u][j] = __hadd2(keep, dpp_xor8_h2(send));
            }
        // level xor16 (swizzle)
        __half2 r2[PFD][2];
#pragma unroll
        for (int u = 0; u < PFD; u++)
#pragma unroll
            for (int j = 0; j < 2; j++) {
                __half2 keep = rb1 ? r1[u][j + 2] : r1[u][j];
                __half2 send = rb1 ? r1[u][j] : r1[u][j + 2];
                r2[u][j] = __hadd2(keep, swz_h2<0x401F>(send));
            }
        // level xor32 (bpermute)
        __half2 r3[PFD];
#pragma unroll
        for (int u = 0; u < PFD; u++) {
            __half2 keep = rb2 ? r2[u][1] : r2[u][0];
            __half2 send = rb2 ? r2[u][0] : r2[u][1];
            int sv = __builtin_amdgcn_ds_bpermute(bperm_addr, h2i(send));
            r3[u] = __hadd2(keep, i2h(sv));
        }
        int cp = cg * 8 + rb0 * 4 + rb1 * 2 + rb2;   // col-pair 0..63
#pragma unroll
        for (int u = 0; u < PFD; u++) {
            size_t m = mbase + t + u;
            if (ATOMIC) {
                float2 f = __half22float2(r3[u]);
                float* op = (float*)outp + m * CC + cp * 2;
                atomicAdd(op, f.x);
                atomicAdd(op + 1, f.y);
            } else {
                ((unsigned*)outp)[((size_t)gi * MROWS + m) * 64 + cp] =
                    (unsigned)h2i(r3[u]);
            }
        }
    }
}

// ---------------------------------------------------------------------------
// Combine f16x2 partials over G groups, apply gate. One dword = 2 cols.
// ---------------------------------------------------------------------------
__global__ __launch_bounds__(256) void combine_kernel(
    const unsigned* __restrict__ opart,
    const float* __restrict__ gbuf, float* __restrict__ ocomb)
{
    size_t idx = (size_t)blockIdx.x * 256 + threadIdx.x;  // < MROWS*64
    float sx = 0.f, sy = 0.f;
#pragma unroll
    for (int gi = 0; gi < GG; ++gi) {
        __half2 h = i2h((int)opart[(size_t)gi * MROWS * 64 + idx]);
        float2 f = __half22float2(h);
        sx += f.x; sy += f.y;
    }
    float2 g = *(const float2*)(gbuf + idx * 2);
    *(float2*)(ocomb + idx * 2) = make_float2(sx * g.x, sy * g.y);
}

__global__ __launch_bounds__(256) void gate_kernel(
    float* __restrict__ ocomb, const float* __restrict__ gbuf)
{
    size_t idx = (size_t)blockIdx.x * 256 + threadIdx.x;
    ocomb[idx] *= gbuf[idx];
}

// ---------------------------------------------------------------------------
extern "C" void kernel_launch(void* const* d_in, const int* in_sizes, int n_in,
                              void* d_out, int out_size, void* d_ws, size_t ws_size,
                              hipStream_t stream)
{
    const float* x  = (const float*)d_in[0];
    const float* Wq = (const float*)d_in[1];
    const float* bq = (const float*)d_in[2];
    const float* Wk = (const float*)d_in[3];
    const float* bk = (const float*)d_in[4];
    const float* Wv = (const float*)d_in[5];
    const float* bv = (const float*)d_in[6];
    const float* Wa = (const float*)d_in[7];
    const float* ba = (const float*)d_in[8];
    const float* Wb = (const float*)d_in[9];
    const float* bb = (const float*)d_in[10];
    const float* Wg = (const float*)d_in[11];
    const float* bg = (const float*)d_in[12];
    const float* Wo = (const float*)d_in[13];
    const float* bo = (const float*)d_in[14];
    float* out = (float*)d_out;

    float* ws = (float*)d_ws;
    size_t off = 0;
    float* Wcat    = ws + off; off += (size_t)DIMK * NPROJ;
    float* biascat = ws + off; off += NPROJ;
    off = (off + 3) & ~(size_t)3;
    float* Y       = ws + off; off += (size_t)MROWS * YSTR;
    float* knorm   = ws + off; off += (size_t)MROWS * CC;
    float* gbuf    = ws + off; off += (size_t)MROWS * CC;
    float* qvab    = ws + off; off += (size_t)MB * GG * TT * 32;
    float* ocomb   = ws + off; off += (size_t)MROWS * CC;
    unsigned* opart = (unsigned*)(ws + off);
    size_t need_big = (off + (size_t)GG * MROWS * 64) * sizeof(float);
    bool big = ws_size >= need_big;

    hipLaunchKernelGGL(pack_w, dim3((DIMK * NPROJ + 255) / 256), dim3(256), 0, stream,
                       Wq, Wk, Wv, Wg, Wa, Wb, Wcat);
    hipLaunchKernelGGL(pack_bias, dim3(1), dim3(NPROJ), 0, stream,
                       bq, bk, bv, bg, ba, bb, biascat);
    hipLaunchKernelGGL(sgemm_bias, dim3(NPROJ / 64, MROWS / 128), dim3(256), 0, stream,
                       x, Wcat, biascat, Y, MROWS, NPROJ, DIMK);
    hipLaunchKernelGGL(postproj_kernel, dim3(MROWS), dim3(64), 0, stream,
                       Y, knorm, gbuf, (float4*)qvab);
    if (big) {
        hipLaunchKernelGGL((scan_kernel<false>), dim3(MB * GG), dim3(64), 0, stream,
                           knorm, (const float4*)qvab, (void*)opart);
        hipLaunchKernelGGL(combine_kernel, dim3(MROWS * 64 / 256), dim3(256), 0, stream,
                           opart, gbuf, ocomb);
    } else {
        (void)hipMemsetAsync(ocomb, 0, (size_t)MROWS * CC * sizeof(float), stream);
        hipLaunchKernelGGL((scan_kernel<true>), dim3(MB * GG), dim3(64), 0, stream,
                           knorm, (const float4*)qvab, (void*)ocomb);
        hipLaunchKernelGGL(gate_kernel, dim3(MROWS * CC / 256), dim3(256), 0, stream,
                           ocomb, gbuf);
    }
    hipLaunchKernelGGL(sgemm_bias, dim3(DIMK / 64, MROWS / 128), dim3(256), 0, stream,
                       ocomb, Wo, bo, out, MROWS, DIMK, CC);
}

// Round 7
// 952.488 us; speedup vs baseline: 1.5897x; 1.2357x over previous
//
#include <hip/hip_runtime.h>
#include <hip/hip_bf16.h>
#include <hip/hip_fp16.h>
#include <cstdint>

#define MB 8
#define TT 2048
#define DIMK 1024
#define CC 128
#define NG 32                 /* groups per batch, 4 rows each */
#define MROWS (MB*TT)         /* 16384 */
#define NPROJ 576
#define YSTR 576

// ---------------------------------------------------------------------------
__global__ void pack_w(const float* __restrict__ Wq, const float* __restrict__ Wk,
                       const float* __restrict__ Wv, const float* __restrict__ Wg,
                       const float* __restrict__ Wa, const float* __restrict__ Wb,
                       float* __restrict__ Wcat)
{
    int idx = blockIdx.x * 256 + threadIdx.x;
    if (idx >= DIMK * NPROJ) return;
    int k = idx / NPROJ, n = idx % NPROJ;
    float v = 0.f;
    if      (n < 128) v = Wq[k * 128 + n];
    else if (n < 256) v = Wk[k * 128 + (n - 128)];
    else if (n < 384) v = Wv[k * 128 + (n - 256)];
    else if (n < 512) v = Wg[k * 128 + (n - 384)];
    else if (n == 512) v = Wa[k];
    else if (n == 513) v = Wb[k];
    Wcat[idx] = v;
}

__global__ void pack_bias(const float* __restrict__ bq, const float* __restrict__ bk,
                          const float* __restrict__ bv, const float* __restrict__ bg,
                          const float* __restrict__ ba, const float* __restrict__ bb,
                          float* __restrict__ biascat)
{
    int n = threadIdx.x;
    if (n >= NPROJ) return;
    float v = 0.f;
    if      (n < 128) v = bq[n];
    else if (n < 256) v = bk[n - 128];
    else if (n < 384) v = bv[n - 256];
    else if (n < 512) v = bg[n - 384];
    else if (n == 512) v = ba[0];
    else if (n == 513) v = bb[0];
    biascat[n] = v;
}

// ---------------------------------------------------------------------------
// Tiled fp32 SGEMM: C[M][N] = A[M][K] @ B[K][N] + bias[N]
// ---------------------------------------------------------------------------
__global__ __launch_bounds__(256) void sgemm_bias(
    const float* __restrict__ A, const float* __restrict__ Bm,
    const float* __restrict__ bias, float* __restrict__ Cm,
    int M, int N, int K)
{
    __shared__ float As[16][128];
    __shared__ float Bs[16][64];
    int tid = threadIdx.x;
    int bm = blockIdx.y * 128;
    int bn = blockIdx.x * 64;
    int tx = tid & 15, ty = tid >> 4;
    float acc[8][4];
#pragma unroll
    for (int u = 0; u < 8; u++)
#pragma unroll
        for (int w = 0; w < 4; w++) acc[u][w] = 0.f;

    for (int kk = 0; kk < K; kk += 16) {
#pragma unroll
        for (int j = 0; j < 2; j++) {
            int fid = tid * 2 + j;
            int row = fid >> 2, kq = fid & 3;
            const float4 av = *(const float4*)(A + (size_t)(bm + row) * K + kk + kq * 4);
            As[kq * 4 + 0][row] = av.x;
            As[kq * 4 + 1][row] = av.y;
            As[kq * 4 + 2][row] = av.z;
            As[kq * 4 + 3][row] = av.w;
        }
        {
            int krow = tid >> 4, c4 = tid & 15;
            const float4 bv = *(const float4*)(Bm + (size_t)(kk + krow) * N + bn + c4 * 4);
            *(float4*)&Bs[krow][c4 * 4] = bv;
        }
        __syncthreads();
#pragma unroll
        for (int kc = 0; kc < 16; kc++) {
            float4 a0 = *(const float4*)&As[kc][ty * 8];
            float4 a1 = *(const float4*)&As[kc][ty * 8 + 4];
            float4 bv = *(const float4*)&Bs[kc][tx * 4];
            float av[8] = {a0.x, a0.y, a0.z, a0.w, a1.x, a1.y, a1.z, a1.w};
            float bw[4] = {bv.x, bv.y, bv.z, bv.w};
#pragma unroll
            for (int u = 0; u < 8; u++)
#pragma unroll
                for (int w = 0; w < 4; w++)
                    acc[u][w] += av[u] * bw[w];
        }
        __syncthreads();
    }
    float4 b4 = *(const float4*)(bias + bn + tx * 4);
#pragma unroll
    for (int u = 0; u < 8; u++) {
        float4 r = make_float4(acc[u][0] + b4.x, acc[u][1] + b4.y,
                               acc[u][2] + b4.z, acc[u][3] + b4.w);
        *(float4*)(Cm + (size_t)(bm + ty * 8 + u) * N + bn + tx * 4) = r;
    }
}

// ---------------------------------------------------------------------------
// Post-projection: k row-normalize, sigmoid(g), (q,v,alpha,beta) packed per
// (group,row-in-group,t) as float4. One wave per row m.
// ---------------------------------------------------------------------------
__global__ __launch_bounds__(64) void postproj_kernel(
    const float* __restrict__ Y, float* __restrict__ knorm,
    float* __restrict__ gbuf, float4* __restrict__ qvab)
{
    int m = blockIdx.x;
    int lane = threadIdx.x;
    int b = m >> 11, t = m & (TT - 1);
    const float* yr = Y + (size_t)m * YSTR;
    float k0 = yr[128 + lane], k1 = yr[192 + lane];
    float ss = k0 * k0 + k1 * k1;
#pragma unroll
    for (int mask = 1; mask < 64; mask <<= 1) ss += __shfl_xor(ss, mask);
    float inv = 1.0f / fmaxf(sqrtf(ss), 1e-12f);
    knorm[(size_t)m * CC + lane]      = k0 * inv;
    knorm[(size_t)m * CC + 64 + lane] = k1 * inv;
    float g0 = yr[384 + lane], g1 = yr[448 + lane];
    gbuf[(size_t)m * CC + lane]      = 1.f / (1.f + expf(-g0));
    gbuf[(size_t)m * CC + 64 + lane] = 1.f / (1.f + expf(-g1));
    float a  = 1.f / (1.f + expf(-yr[512]));
    float bb = 1.f / (1.f + expf(-yr[513]));
    // qvab[((b*NG + i>>2)*TT + t)*4 + (i&3)] = (q_i, v_i, a, b)
    {
        int i = lane;
        qvab[((size_t)(b * NG + (i >> 2)) * TT + t) * 4 + (i & 3)] =
            make_float4(yr[i], yr[256 + i], a, bb);
        i = lane + 64;
        qvab[((size_t)(b * NG + (i >> 2)) * TT + t) * 4 + (i & 3)] =
            make_float4(yr[i], yr[256 + i], a, bb);
    }
}

// ---------------------------------------------------------------------------
// Cross-lane helpers (all ICE-pattern).
// ---------------------------------------------------------------------------
__device__ __forceinline__ float dpp_add_xor1(float p) {
    int i = __builtin_amdgcn_mov_dpp(__float_as_int(p), 0xB1, 0xF, 0xF, true);
    return p + __int_as_float(i);
}
__device__ __forceinline__ float dpp_add_xor2(float p) {
    int i = __builtin_amdgcn_mov_dpp(__float_as_int(p), 0x4E, 0xF, 0xF, true);
    return p + __int_as_float(i);
}
__device__ __forceinline__ float dpp_add_mirror7(float p) {
    // row_half_mirror: i -> i^7 within 8; == xor4 once values uniform mod 4
    int i = __builtin_amdgcn_mov_dpp(__float_as_int(p), 0x141, 0xF, 0xF, true);
    return p + __int_as_float(i);
}
__device__ __forceinline__ float dpp_add_ror8(float p) {
    // row_ror:8 within 16-lane row: i -> i^8
    int i = __builtin_amdgcn_mov_dpp(__float_as_int(p), 0x128, 0xF, 0xF, true);
    return p + __int_as_float(i);
}
__device__ __forceinline__ int h2i(__half2 h) { int i; __builtin_memcpy(&i, &h, 4); return i; }
__device__ __forceinline__ __half2 i2h(int i) { __half2 h; __builtin_memcpy(&h, &i, 4); return h; }
template <int PAT>
__device__ __forceinline__ __half2 swz_h2(__half2 x) {
    return i2h(__builtin_amdgcn_ds_swizzle(h2i(x), PAT));
}
__device__ __forceinline__ float2 f2mul(float2 a, float2 b) {
    return make_float2(a.x * b.x, a.y * b.y);
}
__device__ __forceinline__ float2 f2fma(float2 a, float2 b, float2 c) {
    return make_float2(fmaf(a.x, b.x, c.x), fmaf(a.y, b.y, c.y));
}

// ---------------------------------------------------------------------------
// Sequential scan. Grid = MB*NG single-wave blocks; block (b,gi) owns rows
// [gi*4, gi*4+4). Lanes: cg=lane&15 -> cols [cg*8,cg*8+8), rg=lane>>4 ->
// row gi*4+rg. State = 4 float2/lane. Dot reduction over 16 cg lanes is
// 100% DPP (xor1, xor2, mirror7, ror8). po reduction over 4 rg lanes:
// xor16 swizzle + xor32 bpermute, batched every PFD steps.
// ---------------------------------------------------------------------------
#define PFD 8

template <bool ATOMIC>
__global__ __launch_bounds__(64) void scan_kernel(
    const float* __restrict__ knorm, const float4* __restrict__ qvab,
    void* __restrict__ outp)
{
    int blk = blockIdx.x;
    int b = blk >> 5;
    int gi = blk & 31;
    int lane = threadIdx.x;
    int cg = lane & 15, rg = lane >> 4;
    int rb0 = rg & 1, rb1 = (rg >> 1) & 1;
    float2 s2[4];
#pragma unroll
    for (int c = 0; c < 4; c++) s2[c] = make_float2(0.f, 0.f);
    size_t mbase = (size_t)b * TT;

    const float*  knb = knorm + mbase * CC + cg * 8;
    const float4* qvb = qvab + (size_t)blk * TT * 4 + rg;

    float4 kB[PFD][2];
    float4 qB[PFD];
#pragma unroll
    for (int u = 0; u < PFD; u++) {
        kB[u][0] = *(const float4*)(knb + (size_t)u * CC);
        kB[u][1] = *(const float4*)(knb + (size_t)u * CC + 4);
        qB[u] = qvb[(size_t)u * 4];
    }

    int bperm_addr = (lane ^ 32) << 2;   // xor32 via ds_bpermute

    for (int t = 0; t < TT; t += PFD) {
        __half2 pb[PFD][4];
#pragma unroll
        for (int u = 0; u < PFD; u++) {
            float2 k2[4];
            k2[0] = make_float2(kB[u][0].x, kB[u][0].y);
            k2[1] = make_float2(kB[u][0].z, kB[u][0].w);
            k2[2] = make_float2(kB[u][1].x, kB[u][1].y);
            k2[3] = make_float2(kB[u][1].z, kB[u][1].w);
            float4 qv = qB[u];
            int tp = t + u + PFD;
            if (tp < TT) {
                kB[u][0] = *(const float4*)(knb + (size_t)tp * CC);
                kB[u][1] = *(const float4*)(knb + (size_t)tp * CC + 4);
                qB[u] = qvb[(size_t)tp * 4];
            }
            float q = qv.x, v = qv.y, at = qv.z, bt = qv.w;
            // dot p = s.k
            float2 a0 = f2mul(s2[0], k2[0]);
            float2 a1 = f2mul(s2[1], k2[1]);
            a0 = f2fma(s2[2], k2[2], a0);
            a1 = f2fma(s2[3], k2[3], a1);
            float p = (a0.x + a1.x) + (a0.y + a1.y);
            p = dpp_add_xor1(p);
            p = dpp_add_xor2(p);
            p = dpp_add_mirror7(p);
            p = dpp_add_ror8(p);
            float cr = bt * (v - at * p);
            float2 at2 = make_float2(at, at);
            float2 cr2 = make_float2(cr, cr);
            float2 q2  = make_float2(q, q);
#pragma unroll
            for (int c = 0; c < 4; c++) {
                s2[c] = f2fma(k2[c], cr2, f2mul(s2[c], at2));
                pb[u][c] = __float22half2_rn(f2mul(q2, s2[c]));
            }
        }
        // ---- batched po reduction over rg lanes ----
        // level xor16 (swizzle)
        __half2 r1[PFD][2];
#pragma unroll
        for (int u = 0; u < PFD; u++)
#pragma unroll
            for (int j = 0; j < 2; j++) {
                __half2 keep = rb0 ? pb[u][j + 2] : pb[u][j];
                __half2 send = rb0 ? pb[u][j] : pb[u][j + 2];
                r1[u][j] = __hadd2(keep, swz_h2<0x401F>(send));
            }
        // level xor32 (bpermute)
        __half2 r2[PFD];
#pragma unroll
        for (int u = 0; u < PFD; u++) {
            __half2 keep = rb1 ? r1[u][1] : r1[u][0];
            __half2 send = rb1 ? r1[u][0] : r1[u][1];
            int sv = __builtin_amdgcn_ds_bpermute(bperm_addr, h2i(send));
            r2[u] = __hadd2(keep, i2h(sv));
        }
        int cp = cg * 4 + rb0 * 2 + rb1;   // col-pair 0..63
#pragma unroll
        for (int u = 0; u < PFD; u++) {
            size_t m = mbase + t + u;
            if (ATOMIC) {
                float2 f = __half22float2(r2[u]);
                float* op = (float*)outp + m * CC + cp * 2;
                atomicAdd(op, f.x);
                atomicAdd(op + 1, f.y);
            } else {
                ((unsigned*)outp)[((size_t)gi * MROWS + m) * 64 + cp] =
                    (unsigned)h2i(r2[u]);
            }
        }
    }
}

// ---------------------------------------------------------------------------
// Combine f16x2 partials over NG groups, apply gate. One dword = 2 cols.
// ---------------------------------------------------------------------------
__global__ __launch_bounds__(256) void combine_kernel(
    const unsigned* __restrict__ opart,
    const float* __restrict__ gbuf, float* __restrict__ ocomb)
{
    size_t idx = (size_t)blockIdx.x * 256 + threadIdx.x;  // < MROWS*64
    float sx = 0.f, sy = 0.f;
#pragma unroll
    for (int gi = 0; gi < NG; ++gi) {
        __half2 h = i2h((int)opart[(size_t)gi * MROWS * 64 + idx]);
        float2 f = __half22float2(h);
        sx += f.x; sy += f.y;
    }
    float2 g = *(const float2*)(gbuf + idx * 2);
    *(float2*)(ocomb + idx * 2) = make_float2(sx * g.x, sy * g.y);
}

__global__ __launch_bounds__(256) void gate_kernel(
    float* __restrict__ ocomb, const float* __restrict__ gbuf)
{
    size_t idx = (size_t)blockIdx.x * 256 + threadIdx.x;
    ocomb[idx] *= gbuf[idx];
}

// ---------------------------------------------------------------------------
extern "C" void kernel_launch(void* const* d_in, const int* in_sizes, int n_in,
                              void* d_out, int out_size, void* d_ws, size_t ws_size,
                              hipStream_t stream)
{
    const float* x  = (const float*)d_in[0];
    const float* Wq = (const float*)d_in[1];
    const float* bq = (const float*)d_in[2];
    const float* Wk = (const float*)d_in[3];
    const float* bk = (const float*)d_in[4];
    const float* Wv = (const float*)d_in[5];
    const float* bv = (const float*)d_in[6];
    const float* Wa = (const float*)d_in[7];
    const float* ba = (const float*)d_in[8];
    const float* Wb = (const float*)d_in[9];
    const float* bb = (const float*)d_in[10];
    const float* Wg = (const float*)d_in[11];
    const float* bg = (const float*)d_in[12];
    const float* Wo = (const float*)d_in[13];
    const float* bo = (const float*)d_in[14];
    float* out = (float*)d_out;

    float* ws = (float*)d_ws;
    size_t off = 0;
    float* Wcat    = ws + off; off += (size_t)DIMK * NPROJ;
    float* biascat = ws + off; off += NPROJ;
    off = (off + 3) & ~(size_t)3;
    float* Y       = ws + off; off += (size_t)MROWS * YSTR;
    float* knorm   = ws + off; off += (size_t)MROWS * CC;
    float* gbuf    = ws + off; off += (size_t)MROWS * CC;
    float* qvab    = ws + off; off += (size_t)MB * NG * TT * 16;
    float* ocomb   = ws + off; off += (size_t)MROWS * CC;
    unsigned* opart = (unsigned*)(ws + off);
    size_t need_big = (off + (size_t)NG * MROWS * 64) * sizeof(float);
    bool big = ws_size >= need_big;

    hipLaunchKernelGGL(pack_w, dim3((DIMK * NPROJ + 255) / 256), dim3(256), 0, stream,
                       Wq, Wk, Wv, Wg, Wa, Wb, Wcat);
    hipLaunchKernelGGL(pack_bias, dim3(1), dim3(NPROJ), 0, stream,
                       bq, bk, bv, bg, ba, bb, biascat);
    hipLaunchKernelGGL(sgemm_bias, dim3(NPROJ / 64, MROWS / 128), dim3(256), 0, stream,
                       x, Wcat, biascat, Y, MROWS, NPROJ, DIMK);
    hipLaunchKernelGGL(postproj_kernel, dim3(MROWS), dim3(64), 0, stream,
                       Y, knorm, gbuf, (float4*)qvab);
    if (big) {
        hipLaunchKernelGGL((scan_kernel<false>), dim3(MB * NG), dim3(64), 0, stream,
                           knorm, (const float4*)qvab, (void*)opart);
        hipLaunchKernelGGL(combine_kernel, dim3(MROWS * 64 / 256), dim3(256), 0, stream,
                           opart, gbuf, ocomb);
    } else {
        (void)hipMemsetAsync(ocomb, 0, (size_t)MROWS * CC * sizeof(float), stream);
        hipLaunchKernelGGL((scan_kernel<true>), dim3(MB * NG), dim3(64), 0, stream,
                           knorm, (const float4*)qvab, (void*)ocomb);
        hipLaunchKernelGGL(gate_kernel, dim3(MROWS * CC / 256), dim3(256), 0, stream,
                           ocomb, gbuf);
    }
    hipLaunchKernelGGL(sgemm_bias, dim3(DIMK / 64, MROWS / 128), dim3(256), 0, stream,
                       ocomb, Wo, bo, out, MROWS, DIMK, CC);
}

// Round 8
// 699.090 us; speedup vs baseline: 2.1659x; 1.3625x over previous
//
#include <hip/hip_runtime.h>
#include <hip/hip_fp16.h>
#include <cstdint>

#define MB 8
#define TT 2048
#define DIMK 1024
#define CC 128
#define NG 32                 /* scan groups per batch, 4 rows each */
#define MROWS (MB*TT)         /* 16384 */
#define NPROJ 576
#define YSTR 576

using bf16x8 = __attribute__((__ext_vector_type__(8))) __bf16;
using f32x4v = __attribute__((__ext_vector_type__(4))) float;

__device__ __forceinline__ unsigned short f2b(float f) {
    unsigned u = __float_as_uint(f);
    u += 0x7fffu + ((u >> 16) & 1u);
    return (unsigned short)(u >> 16);
}

// ---------------------------------------------------------------------------
// Casts / packing
// ---------------------------------------------------------------------------
__global__ __launch_bounds__(256) void cast_x_kernel(
    const float* __restrict__ in, unsigned short* __restrict__ outp)
{
    size_t i = ((size_t)blockIdx.x * 256 + threadIdx.x) * 8;
    float4 a = *(const float4*)(in + i);
    float4 b = *(const float4*)(in + i + 4);
    uint4 r;
    r.x = f2b(a.x) | ((unsigned)f2b(a.y) << 16);
    r.y = f2b(a.z) | ((unsigned)f2b(a.w) << 16);
    r.z = f2b(b.x) | ((unsigned)f2b(b.y) << 16);
    r.w = f2b(b.z) | ((unsigned)f2b(b.w) << 16);
    *(uint4*)(outp + i) = r;
}

// WcatT[n][k] bf16, n in [0,576): 0-127 Wq, ... 512 Wa, 513 Wb, rest 0.
__global__ __launch_bounds__(256) void pack_wt(
    const float* __restrict__ Wq, const float* __restrict__ Wk,
    const float* __restrict__ Wv, const float* __restrict__ Wg,
    const float* __restrict__ Wa, const float* __restrict__ Wb,
    unsigned short* __restrict__ WcatT)
{
    int idx = blockIdx.x * 256 + threadIdx.x;
    if (idx >= NPROJ * DIMK) return;
    int n = idx >> 10, k = idx & 1023;
    float v = 0.f;
    if      (n < 128) v = Wq[k * 128 + n];
    else if (n < 256) v = Wk[k * 128 + (n - 128)];
    else if (n < 384) v = Wv[k * 128 + (n - 256)];
    else if (n < 512) v = Wg[k * 128 + (n - 384)];
    else if (n == 512) v = Wa[k];
    else if (n == 513) v = Wb[k];
    WcatT[idx] = f2b(v);
}

__global__ void pack_bias(const float* __restrict__ bq, const float* __restrict__ bk,
                          const float* __restrict__ bv, const float* __restrict__ bg,
                          const float* __restrict__ ba, const float* __restrict__ bb,
                          float* __restrict__ biascat)
{
    int n = threadIdx.x;
    if (n >= NPROJ) return;
    float v = 0.f;
    if      (n < 128) v = bq[n];
    else if (n < 256) v = bk[n - 128];
    else if (n < 384) v = bv[n - 256];
    else if (n < 512) v = bg[n - 384];
    else if (n == 512) v = ba[0];
    else if (n == 513) v = bb[0];
    biascat[n] = v;
}

// WoT[n][k] bf16 (Wo is [CC][DIM])
__global__ __launch_bounds__(256) void cast_wot(
    const float* __restrict__ Wo, unsigned short* __restrict__ WoT)
{
    int idx = blockIdx.x * 256 + threadIdx.x;
    if (idx >= DIMK * CC) return;
    int n = idx >> 7, k = idx & 127;
    WoT[idx] = f2b(Wo[k * DIMK + n]);
}

// ---------------------------------------------------------------------------
// BF16 MFMA GEMM: C[M][N] = A[MxK bf16] @ BT[NxK bf16]^T + bias, fp32 out.
// Tile 128(M) x 64(N), BK=32. 256 threads = 4 waves; wave w owns rows
// [w*32, w*32+32). Per wave: 2 row-tiles x 4 col-tiles of 16x16 via
// mfma_f32_16x16x32_bf16. M%128==0, N%64==0, K%32==0.
// ---------------------------------------------------------------------------
__global__ __launch_bounds__(256) void gemm_bt_bf16(
    const unsigned short* __restrict__ A, const unsigned short* __restrict__ BT,
    const float* __restrict__ bias, float* __restrict__ C,
    int M, int N, int K)
{
    __shared__ unsigned short As[4][128][8];   // [k-quad][m][j]
    __shared__ unsigned short Bs[4][64][8];    // [k-quad][n][j]
    int tid = threadIdx.x;
    int w = tid >> 6, l = tid & 63;
    int lm = l & 15, lq = l >> 4;
    int bm = blockIdx.y * 128, bn = blockIdx.x * 64;

    f32x4v acc[2][4];
#pragma unroll
    for (int rt = 0; rt < 2; rt++)
#pragma unroll
        for (int ct = 0; ct < 4; ct++) acc[rt][ct] = (f32x4v)(0.f);

    int ar = tid >> 1, ah = tid & 1;          // A stage: row ar, 16-elem half ah
    int brn = tid >> 2, bq = tid & 3;         // B stage: row brn, 8-elem quarter
    const unsigned short* Arow = A + (size_t)(bm + ar) * K + ah * 16;
    const unsigned short* Brow = BT + (size_t)(bn + brn) * K + bq * 8;

    for (int kk = 0; kk < K; kk += 32) {
        uint4 av0 = *(const uint4*)(Arow + kk);
        uint4 av1 = *(const uint4*)(Arow + kk + 8);
        uint4 bv  = *(const uint4*)(Brow + kk);
        __syncthreads();
        *(uint4*)&As[ah * 2][ar][0]     = av0;
        *(uint4*)&As[ah * 2 + 1][ar][0] = av1;
        *(uint4*)&Bs[bq][brn][0]        = bv;
        __syncthreads();
        bf16x8 af[2], bf[4];
#pragma unroll
        for (int rt = 0; rt < 2; rt++)
            __builtin_memcpy(&af[rt], &As[lq][w * 32 + rt * 16 + lm][0], 16);
#pragma unroll
        for (int ct = 0; ct < 4; ct++)
            __builtin_memcpy(&bf[ct], &Bs[lq][ct * 16 + lm][0], 16);
#pragma unroll
        for (int rt = 0; rt < 2; rt++)
#pragma unroll
            for (int ct = 0; ct < 4; ct++)
                acc[rt][ct] = __builtin_amdgcn_mfma_f32_16x16x32_bf16(
                    af[rt], bf[ct], acc[rt][ct], 0, 0, 0);
    }
#pragma unroll
    for (int rt = 0; rt < 2; rt++)
#pragma unroll
        for (int ct = 0; ct < 4; ct++) {
            int col = bn + ct * 16 + lm;
            float bcol = bias[col];
#pragma unroll
            for (int i = 0; i < 4; i++) {
                int row = bm + w * 32 + rt * 16 + lq * 4 + i;
                C[(size_t)row * N + col] = acc[rt][ct][i] + bcol;
            }
        }
}

// ---------------------------------------------------------------------------
// Post-projection (unchanged from R7)
// ---------------------------------------------------------------------------
__global__ __launch_bounds__(64) void postproj_kernel(
    const float* __restrict__ Y, float* __restrict__ knorm,
    float* __restrict__ gbuf, float4* __restrict__ qvab)
{
    int m = blockIdx.x;
    int lane = threadIdx.x;
    int b = m >> 11, t = m & (TT - 1);
    const float* yr = Y + (size_t)m * YSTR;
    float k0 = yr[128 + lane], k1 = yr[192 + lane];
    float ss = k0 * k0 + k1 * k1;
#pragma unroll
    for (int mask = 1; mask < 64; mask <<= 1) ss += __shfl_xor(ss, mask);
    float inv = 1.0f / fmaxf(sqrtf(ss), 1e-12f);
    knorm[(size_t)m * CC + lane]      = k0 * inv;
    knorm[(size_t)m * CC + 64 + lane] = k1 * inv;
    float g0 = yr[384 + lane], g1 = yr[448 + lane];
    gbuf[(size_t)m * CC + lane]      = 1.f / (1.f + expf(-g0));
    gbuf[(size_t)m * CC + 64 + lane] = 1.f / (1.f + expf(-g1));
    float a  = 1.f / (1.f + expf(-yr[512]));
    float bb = 1.f / (1.f + expf(-yr[513]));
    {
        int i = lane;
        qvab[((size_t)(b * NG + (i >> 2)) * TT + t) * 4 + (i & 3)] =
            make_float4(yr[i], yr[256 + i], a, bb);
        i = lane + 64;
        qvab[((size_t)(b * NG + (i >> 2)) * TT + t) * 4 + (i & 3)] =
            make_float4(yr[i], yr[256 + i], a, bb);
    }
}

// ---------------------------------------------------------------------------
// Cross-lane helpers
// ---------------------------------------------------------------------------
__device__ __forceinline__ float dpp_add_xor1(float p) {
    int i = __builtin_amdgcn_mov_dpp(__float_as_int(p), 0xB1, 0xF, 0xF, true);
    return p + __int_as_float(i);
}
__device__ __forceinline__ float dpp_add_xor2(float p) {
    int i = __builtin_amdgcn_mov_dpp(__float_as_int(p), 0x4E, 0xF, 0xF, true);
    return p + __int_as_float(i);
}
__device__ __forceinline__ float dpp_add_mirror7(float p) {
    int i = __builtin_amdgcn_mov_dpp(__float_as_int(p), 0x141, 0xF, 0xF, true);
    return p + __int_as_float(i);
}
__device__ __forceinline__ float dpp_add_ror8(float p) {
    int i = __builtin_amdgcn_mov_dpp(__float_as_int(p), 0x128, 0xF, 0xF, true);
    return p + __int_as_float(i);
}
__device__ __forceinline__ int h2i(__half2 h) { int i; __builtin_memcpy(&i, &h, 4); return i; }
__device__ __forceinline__ __half2 i2h(int i) { __half2 h; __builtin_memcpy(&h, &i, 4); return h; }
template <int PAT>
__device__ __forceinline__ __half2 swz_h2(__half2 x) {
    return i2h(__builtin_amdgcn_ds_swizzle(h2i(x), PAT));
}
__device__ __forceinline__ float2 f2mul(float2 a, float2 b) {
    return make_float2(a.x * b.x, a.y * b.y);
}
__device__ __forceinline__ float2 f2fma(float2 a, float2 b, float2 c) {
    return make_float2(fmaf(a.x, b.x, c.x), fmaf(a.y, b.y, c.y));
}

// ---------------------------------------------------------------------------
// Sequential scan (unchanged from R7). Grid = MB*NG single-wave blocks.
// ---------------------------------------------------------------------------
#define PFD 8

template <bool ATOMIC>
__global__ __launch_bounds__(64) void scan_kernel(
    const float* __restrict__ knorm, const float4* __restrict__ qvab,
    void* __restrict__ outp)
{
    int blk = blockIdx.x;
    int b = blk >> 5;
    int gi = blk & 31;
    int lane = threadIdx.x;
    int cg = lane & 15, rg = lane >> 4;
    int rb0 = rg & 1, rb1 = (rg >> 1) & 1;
    float2 s2[4];
#pragma unroll
    for (int c = 0; c < 4; c++) s2[c] = make_float2(0.f, 0.f);
    size_t mbase = (size_t)b * TT;

    const float*  knb = knorm + mbase * CC + cg * 8;
    const float4* qvb = qvab + (size_t)blk * TT * 4 + rg;

    float4 kB[PFD][2];
    float4 qB[PFD];
#pragma unroll
    for (int u = 0; u < PFD; u++) {
        kB[u][0] = *(const float4*)(knb + (size_t)u * CC);
        kB[u][1] = *(const float4*)(knb + (size_t)u * CC + 4);
        qB[u] = qvb[(size_t)u * 4];
    }

    int bperm_addr = (lane ^ 32) << 2;

    for (int t = 0; t < TT; t += PFD) {
        __half2 pb[PFD][4];
#pragma unroll
        for (int u = 0; u < PFD; u++) {
            float2 k2[4];
            k2[0] = make_float2(kB[u][0].x, kB[u][0].y);
            k2[1] = make_float2(kB[u][0].z, kB[u][0].w);
            k2[2] = make_float2(kB[u][1].x, kB[u][1].y);
            k2[3] = make_float2(kB[u][1].z, kB[u][1].w);
            float4 qv = qB[u];
            int tp = t + u + PFD;
            if (tp < TT) {
                kB[u][0] = *(const float4*)(knb + (size_t)tp * CC);
                kB[u][1] = *(const float4*)(knb + (size_t)tp * CC + 4);
                qB[u] = qvb[(size_t)tp * 4];
            }
            float q = qv.x, v = qv.y, at = qv.z, bt = qv.w;
            float2 a0 = f2mul(s2[0], k2[0]);
            float2 a1 = f2mul(s2[1], k2[1]);
            a0 = f2fma(s2[2], k2[2], a0);
            a1 = f2fma(s2[3], k2[3], a1);
            float p = (a0.x + a1.x) + (a0.y + a1.y);
            p = dpp_add_xor1(p);
            p = dpp_add_xor2(p);
            p = dpp_add_mirror7(p);
            p = dpp_add_ror8(p);
            float cr = bt * (v - at * p);
            float2 at2 = make_float2(at, at);
            float2 cr2 = make_float2(cr, cr);
            float2 q2  = make_float2(q, q);
#pragma unroll
            for (int c = 0; c < 4; c++) {
                s2[c] = f2fma(k2[c], cr2, f2mul(s2[c], at2));
                pb[u][c] = __float22half2_rn(f2mul(q2, s2[c]));
            }
        }
        __half2 r1[PFD][2];
#pragma unroll
        for (int u = 0; u < PFD; u++)
#pragma unroll
            for (int j = 0; j < 2; j++) {
                __half2 keep = rb0 ? pb[u][j + 2] : pb[u][j];
                __half2 send = rb0 ? pb[u][j] : pb[u][j + 2];
                r1[u][j] = __hadd2(keep, swz_h2<0x401F>(send));
            }
        __half2 r2[PFD];
#pragma unroll
        for (int u = 0; u < PFD; u++) {
            __half2 keep = rb1 ? r1[u][1] : r1[u][0];
            __half2 send = rb1 ? r1[u][0] : r1[u][1];
            int sv = __builtin_amdgcn_ds_bpermute(bperm_addr, h2i(send));
            r2[u] = __hadd2(keep, i2h(sv));
        }
        int cp = cg * 4 + rb0 * 2 + rb1;
#pragma unroll
        for (int u = 0; u < PFD; u++) {
            size_t m = mbase + t + u;
            if (ATOMIC) {
                float2 f = __half22float2(r2[u]);
                float* op = (float*)outp + m * CC + cp * 2;
                atomicAdd(op, f.x);
                atomicAdd(op + 1, f.y);
            } else {
                ((unsigned*)outp)[((size_t)gi * MROWS + m) * 64 + cp] =
                    (unsigned)h2i(r2[u]);
            }
        }
    }
}

// ---------------------------------------------------------------------------
// Combine f16x2 partials over NG groups, apply gate, emit bf16 pair.
// ---------------------------------------------------------------------------
__global__ __launch_bounds__(256) void combine_kernel(
    const unsigned* __restrict__ opart,
    const float* __restrict__ gbuf, unsigned* __restrict__ ocombb)
{
    size_t idx = (size_t)blockIdx.x * 256 + threadIdx.x;  // < MROWS*64
    float sx = 0.f, sy = 0.f;
#pragma unroll
    for (int gi = 0; gi < NG; ++gi) {
        __half2 h = i2h((int)opart[(size_t)gi * MROWS * 64 + idx]);
        float2 f = __half22float2(h);
        sx += f.x; sy += f.y;
    }
    float2 g = *(const float2*)(gbuf + idx * 2);
    ocombb[idx] = f2b(sx * g.x) | ((unsigned)f2b(sy * g.y) << 16);
}

__global__ __launch_bounds__(256) void gate_kernel(
    const float* __restrict__ ocombf, const float* __restrict__ gbuf,
    unsigned short* __restrict__ ocombb)
{
    size_t idx = (size_t)blockIdx.x * 256 + threadIdx.x;  // < MROWS*CC
    ocombb[idx] = f2b(ocombf[idx] * gbuf[idx]);
}

// ---------------------------------------------------------------------------
extern "C" void kernel_launch(void* const* d_in, const int* in_sizes, int n_in,
                              void* d_out, int out_size, void* d_ws, size_t ws_size,
                              hipStream_t stream)
{
    const float* x  = (const float*)d_in[0];
    const float* Wq = (const float*)d_in[1];
    const float* bq = (const float*)d_in[2];
    const float* Wk = (const float*)d_in[3];
    const float* bk = (const float*)d_in[4];
    const float* Wv = (const float*)d_in[5];
    const float* bv = (const float*)d_in[6];
    const float* Wa = (const float*)d_in[7];
    const float* ba = (const float*)d_in[8];
    const float* Wb = (const float*)d_in[9];
    const float* bb = (const float*)d_in[10];
    const float* Wg = (const float*)d_in[11];
    const float* bg = (const float*)d_in[12];
    const float* Wo = (const float*)d_in[13];
    const float* bo = (const float*)d_in[14];
    float* out = (float*)d_out;

    // ---- workspace layout (floats), with aliasing:
    //  qvab aliases xb (xb dead after proj GEMM; qvab written by postproj)
    //  opart aliases Y and beyond (Y dead after postproj)
    //  ocombf (atomic fallback) aliases opart
    float* ws = (float*)d_ws;
    size_t off = 0;
    float* knorm   = ws + off; off += (size_t)MROWS * CC;        // 2.10M
    float* gbuf    = ws + off; off += (size_t)MROWS * CC;        // 2.10M
    unsigned* ocombb = (unsigned*)(ws + off); off += (size_t)MROWS * CC / 2;
    unsigned short* WcatT = (unsigned short*)(ws + off); off += (size_t)NPROJ * DIMK / 2;
    unsigned short* WoT   = (unsigned short*)(ws + off); off += (size_t)DIMK * CC / 2;
    float* biascat = ws + off; off += NPROJ;
    unsigned short* xb = (unsigned short*)(ws + off);
    float* qvab    = ws + off; off += (size_t)MROWS * DIMK / 2;  // 8.39M (both)
    float* Y       = ws + off;
    size_t opart_off = off;
    off += (size_t)MROWS * YSTR;                                  // Y end
    float* ocombf  = ws + opart_off;
    unsigned* opart = (unsigned*)(ws + opart_off);
    size_t opart_end = opart_off + (size_t)NG * MROWS * 64;
    size_t need_big = (opart_end > off ? opart_end : off) * sizeof(float);
    bool big = ws_size >= need_big;

    hipLaunchKernelGGL(cast_x_kernel, dim3((size_t)MROWS * DIMK / 8 / 256), dim3(256), 0, stream,
                       x, xb);
    hipLaunchKernelGGL(pack_wt, dim3(NPROJ * DIMK / 256), dim3(256), 0, stream,
                       Wq, Wk, Wv, Wg, Wa, Wb, WcatT);
    hipLaunchKernelGGL(pack_bias, dim3(1), dim3(NPROJ), 0, stream,
                       bq, bk, bv, bg, ba, bb, biascat);
    hipLaunchKernelGGL(cast_wot, dim3(DIMK * CC / 256), dim3(256), 0, stream,
                       Wo, WoT);
    // projection GEMM: Y[16384][576] = xb @ WcatT^T + biascat
    hipLaunchKernelGGL(gemm_bt_bf16, dim3(NPROJ / 64, MROWS / 128), dim3(256), 0, stream,
                       xb, WcatT, biascat, Y, MROWS, NPROJ, DIMK);
    hipLaunchKernelGGL(postproj_kernel, dim3(MROWS), dim3(64), 0, stream,
                       Y, knorm, gbuf, (float4*)qvab);
    if (big) {
        hipLaunchKernelGGL((scan_kernel<false>), dim3(MB * NG), dim3(64), 0, stream,
                           knorm, (const float4*)qvab, (void*)opart);
        hipLaunchKernelGGL(combine_kernel, dim3(MROWS * 64 / 256), dim3(256), 0, stream,
                           opart, gbuf, ocombb);
    } else {
        (void)hipMemsetAsync(ocombf, 0, (size_t)MROWS * CC * sizeof(float), stream);
        hipLaunchKernelGGL((scan_kernel<true>), dim3(MB * NG), dim3(64), 0, stream,
                           knorm, (const float4*)qvab, (void*)ocombf);
        hipLaunchKernelGGL(gate_kernel, dim3(MROWS * CC / 256), dim3(256), 0, stream,
                           ocombf, gbuf, (unsigned short*)ocombb);
    }
    // output GEMM: out[16384][1024] = ocombb @ WoT^T + bo
    hipLaunchKernelGGL(gemm_bt_bf16, dim3(DIMK / 64, MROWS / 128), dim3(256), 0, stream,
                       (const unsigned short*)ocombb, WoT, bo, out, MROWS, DIMK, CC);
}